// Round 6
// baseline (1523.354 us; speedup 1.0000x reference)
//
#include <hip/hip_runtime.h>
#include <hip/hip_bf16.h>
#include <math.h>

typedef unsigned short u16;
typedef unsigned int   u32;
typedef __attribute__((ext_vector_type(8))) short short8;
typedef __attribute__((ext_vector_type(4))) float f32x4;

#define B_SZ     2
#define LSEQ     2048
#define DMODEL   2048
#define INTER    4096
#define HEADS    64
#define NSTATE   128
#define CONV_DIM 4352            /* INTER + 2*128 */
#define XSTR     8576            /* xall row stride: 4096 gate + 4480 xBC/dt */
#define NMAIN    8192            /* GEMM1 main launch cols [0,8192) */
#define NTAILC   512             /* GEMM1 tail compute cols [8192,8704) */
#define NTAILS   384             /* tail stored cols (8192..8576) */
#define EPS      1e-5f
#define QCH      64              /* SSD chunk length */
#define NCHUNK   (LSEQ / QCH)    /* 32 */

__device__ __forceinline__ float bf2f(u16 u) {
    u32 v = ((u32)u) << 16;
    return __builtin_bit_cast(float, v);
}
__device__ __forceinline__ u16 f2bf(float x) {
    __hip_bfloat16 h = __float2bfloat16(x);   // RNE
    return __builtin_bit_cast(u16, h);
}
__device__ __forceinline__ u32 pack2(float lo, float hi) {
    return (u32)f2bf(lo) | ((u32)f2bf(hi) << 16);
}
__device__ __forceinline__ void gl2lds16(const void* g, void* l) {
    __builtin_amdgcn_global_load_lds(
        (const __attribute__((address_space(1))) u32*)g,
        (__attribute__((address_space(3))) u32*)l, 16, 0, 0);
}

// ---------------------------------------------------------------------------
// fp32 -> bf16 elementwise (n4 = count/4)
// ---------------------------------------------------------------------------
__global__ __launch_bounds__(256) void cvt_f32_bf16(
    const float* __restrict__ in, u16* __restrict__ out, int n4)
{
    int i = blockIdx.x * 256 + threadIdx.x;
    if (i >= n4) return;
    float4 v = ((const float4*)in)[i];
    ushort4 o;
    o.x = f2bf(v.x); o.y = f2bf(v.y); o.z = f2bf(v.z); o.w = f2bf(v.w);
    ((ushort4*)out)[i] = o;
}

// ---------------------------------------------------------------------------
// Transpose + convert: in fp32 [R][C] -> out bf16 [C][R]. R,C multiples of 64.
// ---------------------------------------------------------------------------
__global__ __launch_bounds__(256) void tr_f32_bf16(
    const float* __restrict__ in, u16* __restrict__ out, int R, int C)
{
    __shared__ u16 tile[64][68];
    const int r0 = blockIdx.y * 64, c0 = blockIdx.x * 64;
    const int tr = threadIdx.x >> 4, tc = (threadIdx.x & 15) * 4;
    #pragma unroll
    for (int i = 0; i < 4; ++i) {
        int r = tr + i * 16;
        float4 v = *(const float4*)(in + (size_t)(r0 + r) * C + c0 + tc);
        tile[r][tc + 0] = f2bf(v.x);
        tile[r][tc + 1] = f2bf(v.y);
        tile[r][tc + 2] = f2bf(v.z);
        tile[r][tc + 3] = f2bf(v.w);
    }
    __syncthreads();
    #pragma unroll
    for (int i = 0; i < 4; ++i) {
        int oc = tr + i * 16;
        ushort4 o;
        o.x = tile[tc + 0][oc];
        o.y = tile[tc + 1][oc];
        o.z = tile[tc + 2][oc];
        o.w = tile[tc + 3][oc];
        *(ushort4*)(out + (size_t)(c0 + oc) * R + r0 + tc) = o;
    }
}

// ---------------------------------------------------------------------------
// 256x512 bf16 MFMA GEMM, NT form: C[M,N] = A[M,K](lda) @ Bt[N,K](ldb)^T.
// 8 waves (2M x 4N), wave tile 128x128 (acc 8x8 f32x4 = 256 regs), BK=32,
// 96 KiB dbuf LDS. Read:MFMA ratio 0.25 (16 b128 reads / 64 MFMA per wave
// per tile) -> per-CU LDS 1536cyc < MFMA 2458cyc, MFMA-dominant.
// Dependency-ordered reads (a0, b0..b7 first, a(i+1) trailed between MFMA
// rows) so the first MFMA unblocks after 9/16 reads (in-order lgkmcnt).
// LDS swizzle for 64B rows: slot ^= (row>>1)&3 -> 8 distinct 4-bank groups
// per 16-lane quarter = 2-way = free. Staging source pre-swizzled, dest
// linear (global_load_lds requirement).
// grid.z: kbase = z*Kslice, kthis = min(Kslice, K-kbase). fp32 partials:
// slice z goes to Co + z*4096*ldc if z < Z2, else Co2 + (z-Z2)*4096*ldc.
// ---------------------------------------------------------------------------
#define SA(c) (smem + (c) * 24576)
#define SB(c) (smem + (c) * 24576 + 8192)

template<int OUT_BF16>
__global__ __launch_bounds__(512, 2) void gemmw(
    const u16* __restrict__ A, const u16* __restrict__ Bt,
    void* __restrict__ Co, void* __restrict__ Co2, int Z2,
    int K, int Kslice, int lda, int ldb, int ldc, int Nstore)
{
    __shared__ __align__(16) u16 smem[49152];   // 96 KiB
    const int tid  = threadIdx.x;
    const int wave = tid >> 6, lane = tid & 63;
    const int wm = wave >> 2, wn = wave & 3;     // 2M x 4N, wave tile 128x128
    const int lr = lane & 15, lq = lane >> 4;

    // XCD-chunked block swizzle (nwg % 8 == 0 for all our grids)
    const int nbx = gridDim.x;
    const int bid = blockIdx.y * nbx + blockIdx.x;
    const int nwg = nbx * gridDim.y;
    const int cpx = nwg >> 3;
    const int swz = (bid & 7) * cpx + (bid >> 3);
    const int n0 = (swz % nbx) * 512;
    const int m0 = (swz / nbx) * 256;
    const int kbase = blockIdx.z * Kslice;
    const int kthis = (Kslice < K - kbase) ? Kslice : (K - kbase);
    const int nt = kthis >> 5;

    // staging: thread -> row (tid>>2) within a 128-row quarter, slot (tid&3);
    // source colblock pre-swizzled: LDS[r][s] holds global chunk s^((r>>1)&3)
    const int scb8  = (((tid & 3) ^ ((tid >> 3) & 3)) << 3);
    const int lbase = wave << 9;                 // u16: wave*64 lanes*8
    const u16* gA = A  + (size_t)(m0 + (tid >> 2)) * lda + kbase + scb8;
    const u16* gB = Bt + (size_t)(n0 + (tid >> 2)) * ldb + kbase + scb8;

    f32x4 acc[8][8];
    #pragma unroll
    for (int i = 0; i < 8; ++i)
        #pragma unroll
        for (int j = 0; j < 8; ++j) acc[i][j] = (f32x4)0.f;

    // prologue: stage tile0 -> buf0 (A: 2 calls, B: 4 calls), drain, sync
    gl2lds16(gA,                      SA(0) + lbase);
    gl2lds16(gA + (size_t)128 * lda,  SA(0) + 4096 + lbase);
    #pragma unroll
    for (int q = 0; q < 4; ++q)
        gl2lds16(gB + (size_t)(q * 128) * ldb, SB(0) + q * 4096 + lbase);
    __builtin_amdgcn_sched_barrier(0);
    asm volatile("s_waitcnt vmcnt(0)" ::: "memory");
    __builtin_amdgcn_s_barrier();

    const int sws = ((lq ^ ((lr >> 1) & 3)) << 3);   // frag slot (u16 offset)

    for (int t = 0; t < nt; ++t) {
        const int c = t & 1;
        // stage tile t+1 into the other buffer (issued at tile top)
        if (t + 1 < nt) {
            const int k1 = (t + 1) << 5;
            gl2lds16(gA + k1,                     SA(c ^ 1) + lbase);
            gl2lds16(gA + (size_t)128 * lda + k1, SA(c ^ 1) + 4096 + lbase);
            #pragma unroll
            for (int q = 0; q < 4; ++q)
                gl2lds16(gB + (size_t)(q * 128) * ldb + k1, SB(c ^ 1) + q * 4096 + lbase);
        }
        __builtin_amdgcn_sched_barrier(0);

        const u16* Ab = SA(c);
        const u16* Bb = SB(c);
        short8 b8[8];
        short8 ac = *(const short8*)(Ab + (wm * 128 + lr) * 32 + sws);
        #pragma unroll
        for (int j = 0; j < 8; ++j)
            b8[j] = *(const short8*)(Bb + (wn * 128 + j * 16 + lr) * 32 + sws);
        __builtin_amdgcn_s_setprio(1);
        #pragma unroll
        for (int i = 0; i < 8; ++i) {
            short8 an = ac;
            if (i < 7)
                an = *(const short8*)(Ab + (wm * 128 + (i + 1) * 16 + lr) * 32 + sws);
            #pragma unroll
            for (int j = 0; j < 8; ++j)
                acc[i][j] = __builtin_amdgcn_mfma_f32_16x16x32_bf16(
                    ac, b8[j], acc[i][j], 0, 0, 0);
            ac = an;
        }
        __builtin_amdgcn_s_setprio(0);
        __builtin_amdgcn_sched_barrier(0);
        if (t + 1 < nt) {
            // stages issued a full tile (~3000cyc) ago -> drain ~free
            asm volatile("s_waitcnt vmcnt(0)" ::: "memory");
            __builtin_amdgcn_s_barrier();
        }
    }

    // Epilogue: C/D layout col=lr, row=lq*4+r. Pair lanes (lr, lr^1) to pack
    // two adjacent cols; even lane stores rows lq*4+{0,1}, odd rows +{2,3}.
    const int odd = lr & 1;
    float* Cf = (blockIdx.z < (unsigned)Z2)
        ? ((float*)Co  + (size_t)blockIdx.z * 4096 * ldc)
        : ((float*)Co2 + (size_t)(blockIdx.z - Z2) * 4096 * ldc);
    #pragma unroll
    for (int i = 0; i < 8; ++i)
        #pragma unroll
        for (int j = 0; j < 8; ++j) {
            float v0 = acc[i][j][0], v1 = acc[i][j][1];
            float v2 = acc[i][j][2], v3 = acc[i][j][3];
            float n0v = __shfl_xor(v0, 1), n1v = __shfl_xor(v1, 1);
            float n2v = __shfl_xor(v2, 1), n3v = __shfl_xor(v3, 1);
            int colb  = n0 + wn * 128 + j * 16 + (lr & ~1);
            int rbase = m0 + wm * 128 + i * 16 + lq * 4 + odd * 2;
            if ((n0 + wn * 128 + j * 16) < Nstore) {
                if (OUT_BF16) {
                    u32 w0 = odd ? pack2(n2v, v2) : pack2(v0, n0v);
                    u32 w1 = odd ? pack2(n3v, v3) : pack2(v1, n1v);
                    *(u32*)((u16*)Co + (size_t)rbase * ldc + colb) = w0;
                    *(u32*)((u16*)Co + (size_t)(rbase + 1) * ldc + colb) = w1;
                } else {
                    float2 f0 = odd ? make_float2(n2v, v2) : make_float2(v0, n0v);
                    float2 f1 = odd ? make_float2(n3v, v3) : make_float2(v1, n1v);
                    *(float2*)(Cf + (size_t)rbase * ldc + colb) = f0;
                    *(float2*)(Cf + (size_t)(rbase + 1) * ldc + colb) = f1;
                }
            }
        }
}

// ---------------------------------------------------------------------------
// GEMM1 tail combine: xall[row][8192+c] = bf16(sum_z Pt[z][row][c]), c<384.
// Pt: [4][4096][512] f32.
// ---------------------------------------------------------------------------
__global__ __launch_bounds__(256) void tail_add(
    const float* __restrict__ Pt, u16* __restrict__ xall_)
{
    int i = blockIdx.x * 256 + threadIdx.x;      // 4096 rows * 96 col-quads
    int row = i / 96, cq = (i % 96) * 4;
    const float* p = Pt + (size_t)row * NTAILC + cq;
    const size_t zs = (size_t)4096 * NTAILC;
    float4 a = *(const float4*)(p);
    float4 b = *(const float4*)(p + zs);
    float4 c = *(const float4*)(p + 2 * zs);
    float4 d = *(const float4*)(p + 3 * zs);
    ushort4 o;
    o.x = f2bf(a.x + b.x + c.x + d.x);
    o.y = f2bf(a.y + b.y + c.y + d.y);
    o.z = f2bf(a.z + b.z + c.z + d.z);
    o.w = f2bf(a.w + b.w + c.w + d.w);
    *(ushort4*)(xall_ + (size_t)row * XSTR + NMAIN + cq) = o;
}

// ---------------------------------------------------------------------------
// out = a + b + c (fp32, vectorized); c at a separate base.
// ---------------------------------------------------------------------------
__global__ __launch_bounds__(256) void add3_f32(
    const float* __restrict__ a, const float* __restrict__ b,
    const float* __restrict__ c, float* __restrict__ o, int n4)
{
    int i = blockIdx.x * 256 + threadIdx.x;
    if (i >= n4) return;
    float4 x = ((const float4*)a)[i];
    float4 y = ((const float4*)b)[i];
    float4 z = ((const float4*)c)[i];
    x.x += y.x + z.x; x.y += y.y + z.y; x.z += y.z + z.z; x.w += y.w + z.w;
    ((float4*)o)[i] = x;
}

// ---------------------------------------------------------------------------
// dt = softplus(dt_mm + bias). dt_mm read from xall bf16 cols [8448,8512).
// ---------------------------------------------------------------------------
__global__ void dt_kernel(const u16* __restrict__ xall,
                          float* __restrict__ dtb,
                          const float* __restrict__ dt_bias, int n)
{
    int i = blockIdx.x * 256 + threadIdx.x;
    if (i >= n) return;
    int h = i & 63, row = i >> 6;
    float x = bf2f(xall[(size_t)row * XSTR + INTER + CONV_DIM + h]) + dt_bias[h];
    dtb[i] = (x < 10.f) ? log1pf(expf(x)) : x;
}

// ---------------------------------------------------------------------------
// Causal depthwise conv1d (K=4) + bias + silu. Input = xall cols [4096,8448).
// 4 channels/thread, ushort4 taps.
// ---------------------------------------------------------------------------
__global__ __launch_bounds__(256) void conv_kernel(
    const u16* __restrict__ xall, const float* __restrict__ cw,
    const float* __restrict__ cb, u16* __restrict__ xout)
{
    int c4 = blockIdx.x * 256 + threadIdx.x;   // 0..1087
    if (c4 >= CONV_DIM / 4) return;
    int c  = c4 * 4;
    int bt = blockIdx.y;
    int t  = bt & (LSEQ - 1);
    const u16* xi = xall + (size_t)bt * XSTR + INTER + c;
    float4 w0 = *(const float4*)(cw + (size_t)(c + 0) * 4);
    float4 w1 = *(const float4*)(cw + (size_t)(c + 1) * 4);
    float4 w2 = *(const float4*)(cw + (size_t)(c + 2) * 4);
    float4 w3 = *(const float4*)(cw + (size_t)(c + 3) * 4);
    float4 bb = *(const float4*)(cb + c);
    float a0 = bb.x, a1 = bb.y, a2 = bb.z, a3 = bb.w;
    ushort4 x0 = *(const ushort4*)(xi);
    a0 = fmaf(bf2f(x0.x), w0.w, a0); a1 = fmaf(bf2f(x0.y), w1.w, a1);
    a2 = fmaf(bf2f(x0.z), w2.w, a2); a3 = fmaf(bf2f(x0.w), w3.w, a3);
    if (t >= 1) {
        ushort4 xm = *(const ushort4*)(xi - XSTR);
        a0 = fmaf(bf2f(xm.x), w0.z, a0); a1 = fmaf(bf2f(xm.y), w1.z, a1);
        a2 = fmaf(bf2f(xm.z), w2.z, a2); a3 = fmaf(bf2f(xm.w), w3.z, a3);
    }
    if (t >= 2) {
        ushort4 xm = *(const ushort4*)(xi - 2 * XSTR);
        a0 = fmaf(bf2f(xm.x), w0.y, a0); a1 = fmaf(bf2f(xm.y), w1.y, a1);
        a2 = fmaf(bf2f(xm.z), w2.y, a2); a3 = fmaf(bf2f(xm.w), w3.y, a3);
    }
    if (t >= 3) {
        ushort4 xm = *(const ushort4*)(xi - 3 * XSTR);
        a0 = fmaf(bf2f(xm.x), w0.x, a0); a1 = fmaf(bf2f(xm.y), w1.x, a1);
        a2 = fmaf(bf2f(xm.z), w2.x, a2); a3 = fmaf(bf2f(xm.w), w3.x, a3);
    }
    ushort4 o;
    o.x = f2bf(a0 / (1.f + expf(-a0)));
    o.y = f2bf(a1 / (1.f + expf(-a1)));
    o.z = f2bf(a2 / (1.f + expf(-a2)));
    o.w = f2bf(a3 / (1.f + expf(-a3)));
    *(ushort4*)(xout + (size_t)bt * CONV_DIM + c) = o;
}

// ---------------------------------------------------------------------------
// SSD pass 1: T[p][n] = sum_j Xw[j][p] B[j][n], Xw = dt_j e^{cumQ-cum_j} x.
// ---------------------------------------------------------------------------
__global__ __launch_bounds__(256) void ssd_chunk_state(
    const u16* __restrict__ xc, const float* __restrict__ dtb,
    const float* __restrict__ A_log,
    u16* __restrict__ Tg, float* __restrict__ decayQ)
{
    const int bid = blockIdx.x;
    const int b = bid >> 11, h = (bid >> 5) & 63, c = bid & 31;
    const int t0 = c * QCH;
    const int tid = threadIdx.x;
    const int wave = tid >> 6, lane = tid & 63;
    const int lr = lane & 15, lq = lane >> 4;

    __shared__ __align__(16) u16 BT[128][72];   // B^T: [n][j]
    __shared__ __align__(16) u16 XwT[64][72];   // Xw^T: [p][j]
    __shared__ float sclL[QCH];

    const u16* xg = xc + (size_t)b * LSEQ * CONV_DIM;

    if (tid < 64) {
        float dtv = dtb[((size_t)b * LSEQ + t0 + tid) * HEADS + h];
        float a = -dtv * expf(A_log[h]);
        float s = a;
        #pragma unroll
        for (int off = 1; off < 64; off <<= 1) {
            float o = __shfl_up(s, off, 64);
            if (tid >= off) s += o;
        }
        float cq = __shfl(s, 63, 64);
        sclL[tid] = dtv * expf(cq - s);
        if (tid == 0) decayQ[((b * 64 + h) << 5) + c] = expf(cq);
    }
    __syncthreads();

    #pragma unroll
    for (int r = 0; r < 16; ++r) {
        int idx = tid + 256 * r, j = idx >> 6, p = idx & 63;
        float v = bf2f(xg[(size_t)(t0 + j) * CONV_DIM + h * 64 + p]);
        XwT[p][j] = f2bf(v * sclL[j]);
    }
    #pragma unroll
    for (int r = 0; r < 32; ++r) {
        int idx = tid + 256 * r, j = idx >> 7, n = idx & 127;
        BT[n][j] = xg[(size_t)(t0 + j) * CONV_DIM + INTER + n];
    }
    __syncthreads();

    f32x4 acc[8];
    #pragma unroll
    for (int i = 0; i < 8; ++i) acc[i] = (f32x4)0.f;
    #pragma unroll
    for (int k0 = 0; k0 < QCH; k0 += 32) {
        short8 af = *(const short8*)&XwT[wave * 16 + lr][k0 + lq * 8];
        #pragma unroll
        for (int nt = 0; nt < 8; ++nt) {
            short8 bfr = *(const short8*)&BT[nt * 16 + lr][k0 + lq * 8];
            acc[nt] = __builtin_amdgcn_mfma_f32_16x16x32_bf16(af, bfr, acc[nt], 0, 0, 0);
        }
    }
    u16* To = Tg + ((((size_t)(b * 64 + h)) * NCHUNK + c) * 64) * 128;
    #pragma unroll
    for (int nt = 0; nt < 8; ++nt)
        #pragma unroll
        for (int r = 0; r < 4; ++r)
            To[(wave * 16 + lq * 4 + r) * 128 + nt * 16 + lr] = f2bf(acc[nt][r]);
}

// ---------------------------------------------------------------------------
// SSD pass 2: sequential recurrence over chunk states (in-place).
// 512 blocks: (bh, n-quarter); each thread owns (p, 8 n-elems).
// ---------------------------------------------------------------------------
__global__ __launch_bounds__(256) void ssd_state_scan(
    u16* __restrict__ Tg, const float* __restrict__ decayQ)
{
    const int bh = blockIdx.x >> 2, nq = blockIdx.x & 3;
    const int tid = threadIdx.x;
    const int p = tid >> 2, nb = nq * 32 + (tid & 3) * 8;
    float S[8];
    #pragma unroll
    for (int m = 0; m < 8; ++m) S[m] = 0.f;

    for (int c = 0; c < NCHUNK; ++c) {
        u16* base = Tg + ((((size_t)bh * NCHUNK + c) * 64 + p) * 128) + nb;
        uint4 tv = *(const uint4*)base;
        uint4 sv;
        sv.x = pack2(S[0], S[1]);
        sv.y = pack2(S[2], S[3]);
        sv.z = pack2(S[4], S[5]);
        sv.w = pack2(S[6], S[7]);
        *(uint4*)base = sv;
        float dq = decayQ[(bh << 5) + c];
        const u32* w = (const u32*)&tv;
        #pragma unroll
        for (int e = 0; e < 4; ++e) {
            S[e*2]     = fmaf(dq, S[e*2],     bf2f((u16)(w[e] & 0xffffu)));
            S[e*2 + 1] = fmaf(dq, S[e*2 + 1], bf2f((u16)(w[e] >> 16)));
        }
    }
}

// ---------------------------------------------------------------------------
// SSD pass 3: Y = (C·B^T ∘ M)·X + diag(e^{cum})·(C·S_prev^T) + D·x.
// y written strided (XSTR) into the dead xBC region of xall.
// ---------------------------------------------------------------------------
__global__ __launch_bounds__(256) void ssd_output(
    const u16* __restrict__ xc, const float* __restrict__ dtb,
    const float* __restrict__ A_log, const float* __restrict__ Dvec,
    const u16* __restrict__ Sg,
    u16* __restrict__ y)           // base xall+4096, row stride XSTR
{
    const int bid = blockIdx.x;
    const int b = bid >> 11, h = (bid >> 5) & 63, c = bid & 31;
    const int t0 = c * QCH;
    const int tid = threadIdx.x;
    const int wave = tid >> 6, lane = tid & 63;
    const int lr = lane & 15, lq = lane >> 4;

    __shared__ __align__(16) u16 C_lds[64][136];
    __shared__ __align__(16) u16 B_lds[64][136];
    __shared__ __align__(16) u16 S_lds[64][136];
    __shared__ __align__(16) u16 P_lds[64][72];
    __shared__ __align__(16) u16 XT[64][72];
    __shared__ float cumL[QCH], dtsL[QCH], escL[QCH];

    const u16* xg = xc + (size_t)b * LSEQ * CONV_DIM;

    if (tid < 64) {
        float dtv = dtb[((size_t)b * LSEQ + t0 + tid) * HEADS + h];
        float a = -dtv * expf(A_log[h]);
        float s = a;
        #pragma unroll
        for (int off = 1; off < 64; off <<= 1) {
            float o = __shfl_up(s, off, 64);
            if (tid >= off) s += o;
        }
        cumL[tid] = s;
        dtsL[tid] = dtv;
        escL[tid] = expf(s);
    }
    #pragma unroll
    for (int r4 = 0; r4 < 4; ++r4) {
        int idx4 = tid + 256 * r4;
        int j = idx4 >> 4, c8 = (idx4 & 15) * 8;
        *(uint4*)&B_lds[j][c8] = *(const uint4*)(xg + (size_t)(t0 + j) * CONV_DIM + INTER + c8);
        *(uint4*)&C_lds[j][c8] = *(const uint4*)(xg + (size_t)(t0 + j) * CONV_DIM + INTER + NSTATE + c8);
        *(uint4*)&S_lds[j][c8] = *(const uint4*)(Sg + ((((size_t)(b * 64 + h)) * NCHUNK + c) * 64 + j) * 128 + c8);
    }
    #pragma unroll
    for (int r = 0; r < 16; ++r) {
        int idx = tid + 256 * r, j = idx >> 6, p = idx & 63;
        XT[p][j] = xg[(size_t)(t0 + j) * CONV_DIM + h * 64 + p];
    }
    __syncthreads();

    f32x4 accG[4];
    #pragma unroll
    for (int i = 0; i < 4; ++i) accG[i] = (f32x4)0.f;
    #pragma unroll
    for (int k0 = 0; k0 < NSTATE; k0 += 32) {
        short8 af = *(const short8*)&C_lds[wave * 16 + lr][k0 + lq * 8];
        #pragma unroll
        for (int jt = 0; jt < 4; ++jt) {
            short8 bfr = *(const short8*)&B_lds[jt * 16 + lr][k0 + lq * 8];
            accG[jt] = __builtin_amdgcn_mfma_f32_16x16x32_bf16(af, bfr, accG[jt], 0, 0, 0);
        }
    }
    #pragma unroll
    for (int jt = 0; jt < 4; ++jt)
        #pragma unroll
        for (int r = 0; r < 4; ++r) {
            int ii = wave * 16 + lq * 4 + r;
            int jj = jt * 16 + lr;
            float v = (jj <= ii)
                ? accG[jt][r] * dtsL[jj] * expf(cumL[ii] - cumL[jj]) : 0.f;
            P_lds[ii][jj] = f2bf(v);
        }
    __syncthreads();

    f32x4 accY[4], accZ[4];
    #pragma unroll
    for (int i = 0; i < 4; ++i) { accY[i] = (f32x4)0.f; accZ[i] = (f32x4)0.f; }
    #pragma unroll
    for (int k0 = 0; k0 < QCH; k0 += 32) {
        short8 af = *(const short8*)&P_lds[wave * 16 + lr][k0 + lq * 8];
        #pragma unroll
        for (int pt = 0; pt < 4; ++pt) {
            short8 bfr = *(const short8*)&XT[pt * 16 + lr][k0 + lq * 8];
            accY[pt] = __builtin_amdgcn_mfma_f32_16x16x32_bf16(af, bfr, accY[pt], 0, 0, 0);
        }
    }
    #pragma unroll
    for (int k0 = 0; k0 < NSTATE; k0 += 32) {
        short8 af = *(const short8*)&C_lds[wave * 16 + lr][k0 + lq * 8];
        #pragma unroll
        for (int pt = 0; pt < 4; ++pt) {
            short8 bfr = *(const short8*)&S_lds[pt * 16 + lr][k0 + lq * 8];
            accZ[pt] = __builtin_amdgcn_mfma_f32_16x16x32_bf16(af, bfr, accZ[pt], 0, 0, 0);
        }
    }

    const float Dh = Dvec[h];
    u16* yg = y + ((size_t)b * LSEQ + t0) * XSTR + h * 64;
    #pragma unroll
    for (int pt = 0; pt < 4; ++pt)
        #pragma unroll
        for (int r = 0; r < 4; ++r) {
            int ii = wave * 16 + lq * 4 + r;
            int pp = pt * 16 + lr;
            float xv = bf2f(XT[pp][ii]);
            float o = accY[pt][r] + escL[ii] * accZ[pt][r] + Dh * xv;
            yg[(size_t)ii * XSTR + pp] = f2bf(o);
        }
}

// ---------------------------------------------------------------------------
// Gated RMSNorm (G=1). y = xall cols [4096,8192), gate = cols [0,4096);
// normed bf16 written in-place over gate. Row stride XSTR. Vectorized 8/lane.
// ---------------------------------------------------------------------------
__global__ __launch_bounds__(256) void norm_kernel(
    u16* __restrict__ xall, const float* __restrict__ w)
{
    const int row = blockIdx.x;
    const u16* yr = xall + (size_t)row * XSTR + INTER;
    u16*       gr = xall + (size_t)row * XSTR;
    const int tid = threadIdx.x;

    float v[16];
    float ss = 0.f;
    #pragma unroll
    for (int i = 0; i < 2; ++i) {
        int e0 = i * 2048 + tid * 8;
        uint4 hv4 = *(const uint4*)(yr + e0);
        uint4 gv4 = *(const uint4*)(gr + e0);
        const u16* hp = (const u16*)&hv4;
        const u16* gp = (const u16*)&gv4;
        #pragma unroll
        for (int k = 0; k < 8; ++k) {
            float hv = bf2f(hp[k]);
            float g  = bf2f(gp[k]);
            float val = hv * (g / (1.f + expf(-g)));
            v[i * 8 + k] = val;
            ss = fmaf(val, val, ss);
        }
    }
    #pragma unroll
    for (int o = 32; o > 0; o >>= 1) ss += __shfl_xor(ss, o);
    __shared__ float part[4];
    if ((tid & 63) == 0) part[tid >> 6] = ss;
    __syncthreads();
    float tot  = part[0] + part[1] + part[2] + part[3];
    float rinv = rsqrtf(tot * (1.f / INTER) + EPS);
    #pragma unroll
    for (int i = 0; i < 2; ++i) {
        int e0 = i * 2048 + tid * 8;
        float4 wa = *(const float4*)(w + e0);
        float4 wb = *(const float4*)(w + e0 + 4);
        uint4 sv;
        sv.x = pack2(wa.x * v[i*8+0] * rinv, wa.y * v[i*8+1] * rinv);
        sv.y = pack2(wa.z * v[i*8+2] * rinv, wa.w * v[i*8+3] * rinv);
        sv.z = pack2(wb.x * v[i*8+4] * rinv, wb.y * v[i*8+5] * rinv);
        sv.w = pack2(wb.z * v[i*8+6] * rinv, wb.w * v[i*8+7] * rinv);
        *(uint4*)(gr + e0) = sv;
    }
}

// ---------------------------------------------------------------------------
extern "C" void kernel_launch(void* const* d_in, const int* in_sizes, int n_in,
                              void* d_out, int out_size, void* d_ws, size_t ws_size,
                              hipStream_t stream)
{
    const float* hs      = (const float*)d_in[0];
    const float* W_z     = (const float*)d_in[1];
    const float* W_xBC   = (const float*)d_in[2];
    const float* W_dt    = (const float*)d_in[3];
    const float* conv_w  = (const float*)d_in[4];
    const float* conv_b  = (const float*)d_in[5];
    const float* dt_bias = (const float*)d_in[6];
    const float* A_log   = (const float*)d_in[7];
    const float* Dv      = (const float*)d_in[8];
    const float* norm_w  = (const float*)d_in[9];
    const float* W_out   = (const float*)d_in[10];
    float* out = (float*)d_out;
    char*  w8  = (char*)d_ws;

    // workspace (bytes):
    u16* hs_bf  = (u16*)(w8 + 0);            // 16,777,216
    u16* Wt_all = (u16*)(w8 + 16777216);     // 8704*2048*2 = 35,651,584 (ends 52,428,800)
    u16* Tbuf   = (u16*)(w8 + 0);            // 67,108,864 (alias; SSD phase)
    float* Cp01 = (float*)(w8 + 0);          // 2 x 33,554,432 (alias; GEMM2 phase)
    u16* Wt_out = (u16*)(w8 + 67108864);     // 16,777,216
    u16* xall   = (u16*)(w8 + 83886080);     // 4096*8576*2 = 70,254,592 (ends 154,140,672)
    u16* xconv  = (u16*)(w8 + 154140672);    // 35,651,584
    float* Ptail= (float*)(w8 + 154140672);  // 4*4096*512*4 = 33,554,432 (alias xconv)
    float* Cp2  = (float*)(w8 + 154140672);  // 33,554,432 (alias xconv; GEMM2 phase)
    float* dtb  = (float*)(w8 + 189792256);  // 1,048,576
    float* dcq  = (float*)(w8 + 190840832);  // 16,384 (total 190,857,216)

    const int M = B_SZ * LSEQ;               // 4096

    cvt_f32_bf16<<<(M * DMODEL / 4 + 255) / 256, 256, 0, stream>>>(hs, hs_bf, M * DMODEL / 4);
    // Wt_all rows: [0,4096) = W_z^T, [4096,8448) = W_xBC^T, [8448,8512) = W_dt^T,
    // [8512,8704) = zero pad (tail computes cols up to 8704, stores <8576)
    tr_f32_bf16<<<dim3(INTER / 64,    DMODEL / 64), 256, 0, stream>>>(W_z,   Wt_all, DMODEL, INTER);
    tr_f32_bf16<<<dim3(CONV_DIM / 64, DMODEL / 64), 256, 0, stream>>>(W_xBC, Wt_all + (size_t)INTER * DMODEL, DMODEL, CONV_DIM);
    tr_f32_bf16<<<dim3(1,             DMODEL / 64), 256, 0, stream>>>(W_dt,  Wt_all + (size_t)(INTER + CONV_DIM) * DMODEL, DMODEL, 64);
    hipMemsetAsync(Wt_all + (size_t)(INTER + CONV_DIM + 64) * DMODEL, 0, (size_t)192 * DMODEL * 2, stream);
    tr_f32_bf16<<<dim3(DMODEL / 64,   INTER / 64),  256, 0, stream>>>(W_out, Wt_out, INTER, DMODEL);

    // GEMM1 main: cols [0,8192) -> 16x16 = 256 blocks = exactly ONE round
    gemmw<1><<<dim3(NMAIN / 512, M / 256, 1), 512, 0, stream>>>(
        hs_bf, Wt_all, (void*)xall, nullptr, 8,
        DMODEL /*K*/, DMODEL /*Kslice*/, DMODEL, DMODEL, XSTR /*ldc*/, NMAIN);
    // GEMM1 tail: cols [8192,8704), split-K=4 -> 64 blocks (K=512 each)
    gemmw<0><<<dim3(1, M / 256, 4), 512, 0, stream>>>(
        hs_bf, Wt_all + (size_t)NMAIN * DMODEL, (void*)Ptail, nullptr, 8,
        DMODEL /*K*/, DMODEL / 4 /*Kslice*/, DMODEL, DMODEL, NTAILC /*ldc*/, NTAILS);
    tail_add<<<M * (NTAILS / 4) / 256, 256, 0, stream>>>(Ptail, xall);

    dt_kernel<<<(M * HEADS + 255) / 256, 256, 0, stream>>>(xall, dtb, dt_bias, M * HEADS);
    conv_kernel<<<dim3((CONV_DIM / 4 + 255) / 256, M), 256, 0, stream>>>(xall, conv_w, conv_b, xconv);

    ssd_chunk_state<<<B_SZ * HEADS * NCHUNK, 256, 0, stream>>>(xconv, dtb, A_log, Tbuf, dcq);
    ssd_state_scan<<<B_SZ * HEADS * 4, 256, 0, stream>>>(Tbuf, dcq);
    ssd_output<<<B_SZ * HEADS * NCHUNK, 256, 0, stream>>>(xconv, dtb, A_log, Dv, Tbuf, xall + INTER);

    norm_kernel<<<M, 256, 0, stream>>>(xall, norm_w);

    // out GEMM: split-K=3 (slices 1376/1376/1344) -> 192 blocks; partials:
    // z0,z1 -> Cp01 (contig), z2 -> Cp2 (xconv region); then 3-way add.
    gemmw<0><<<dim3(DMODEL / 512, M / 256, 3), 512, 0, stream>>>(
        xall, Wt_out, (void*)Cp01, (void*)Cp2, 2,
        INTER /*K*/, 1376 /*Kslice*/, XSTR /*lda*/, INTER /*ldb*/,
        DMODEL /*ldc*/, DMODEL);
    add3_f32<<<(M * DMODEL / 4 + 255) / 256, 256, 0, stream>>>(
        Cp01, Cp01 + (size_t)M * DMODEL, Cp2, out, M * DMODEL / 4);
}

// Round 7
// 631.068 us; speedup vs baseline: 2.4139x; 2.4139x over previous
//
#include <hip/hip_runtime.h>
#include <hip/hip_bf16.h>
#include <math.h>

typedef unsigned short u16;
typedef unsigned int   u32;
typedef __attribute__((ext_vector_type(8))) short short8;
typedef __attribute__((ext_vector_type(8))) unsigned short us8;
typedef __attribute__((ext_vector_type(4))) float f32x4;

#define B_SZ     2
#define LSEQ     2048
#define DMODEL   2048
#define INTER    4096
#define HEADS    64
#define NSTATE   128
#define CONV_DIM 4352            /* INTER + 2*128 */
#define XSTR     8576            /* xall row stride: 4096 gate + 4480 xBC/dt */
#define NMAIN    8192            /* GEMM1 main launch cols [0,8192) */
#define NTAILC   512             /* GEMM1 tail compute cols [8192,8704) */
#define NTAILS   384             /* tail stored cols (8192..8576) */
#define EPS      1e-5f
#define QCH      64              /* SSD chunk length */
#define NCHUNK   (LSEQ / QCH)    /* 32 */

__device__ __forceinline__ float bf2f(u16 u) {
    u32 v = ((u32)u) << 16;
    return __builtin_bit_cast(float, v);
}
__device__ __forceinline__ u16 f2bf(float x) {
    __hip_bfloat16 h = __float2bfloat16(x);   // RNE
    return __builtin_bit_cast(u16, h);
}
__device__ __forceinline__ u32 pack2(float lo, float hi) {
    return (u32)f2bf(lo) | ((u32)f2bf(hi) << 16);
}
__device__ __forceinline__ void gl2lds16(const void* g, void* l) {
    __builtin_amdgcn_global_load_lds(
        (const __attribute__((address_space(1))) u32*)g,
        (__attribute__((address_space(3))) u32*)l, 16, 0, 0);
}

// ---------------------------------------------------------------------------
// fp32 -> bf16 elementwise (n4 = count/4)
// ---------------------------------------------------------------------------
__global__ __launch_bounds__(256) void cvt_f32_bf16(
    const float* __restrict__ in, u16* __restrict__ out, int n4)
{
    int i = blockIdx.x * 256 + threadIdx.x;
    if (i >= n4) return;
    float4 v = ((const float4*)in)[i];
    ushort4 o;
    o.x = f2bf(v.x); o.y = f2bf(v.y); o.z = f2bf(v.z); o.w = f2bf(v.w);
    ((ushort4*)out)[i] = o;
}

// ---------------------------------------------------------------------------
// Transpose + convert: in fp32 [R][C] -> out bf16 [C][R]. R,C multiples of 64.
// ---------------------------------------------------------------------------
__global__ __launch_bounds__(256) void tr_f32_bf16(
    const float* __restrict__ in, u16* __restrict__ out, int R, int C)
{
    __shared__ u16 tile[64][68];
    const int r0 = blockIdx.y * 64, c0 = blockIdx.x * 64;
    const int tr = threadIdx.x >> 4, tc = (threadIdx.x & 15) * 4;
    #pragma unroll
    for (int i = 0; i < 4; ++i) {
        int r = tr + i * 16;
        float4 v = *(const float4*)(in + (size_t)(r0 + r) * C + c0 + tc);
        tile[r][tc + 0] = f2bf(v.x);
        tile[r][tc + 1] = f2bf(v.y);
        tile[r][tc + 2] = f2bf(v.z);
        tile[r][tc + 3] = f2bf(v.w);
    }
    __syncthreads();
    #pragma unroll
    for (int i = 0; i < 4; ++i) {
        int oc = tr + i * 16;
        ushort4 o;
        o.x = tile[tc + 0][oc];
        o.y = tile[tc + 1][oc];
        o.z = tile[tc + 2][oc];
        o.w = tile[tc + 3][oc];
        *(ushort4*)(out + (size_t)(c0 + oc) * R + r0 + tc) = o;
    }
}

// ---------------------------------------------------------------------------
// 256x256 8-phase bf16 MFMA GEMM, NT form: C[M,N] = A[M,K](lda) @ Bt[N,K](ldb)^T
// 8 waves (2M x 4N), BK=64, 128 KiB double-buffered XOR-swizzled LDS,
// counted vmcnt (never drained to 0 in steady state), setprio around MFMA.
// Staging schedule (per tile t, 4 phases P1..P4, buffers c=t&1, o=c^1):
//   P1: t+1 A q1,q3 -> o ; P2: t+1 B q0,q1 -> o ; P3: t+1 B q2,q3 -> o
//   P4: t+2 A q0,q2 -> c (rows dead after P3); boundary s_waitcnt vmcnt(2).
// 1 block/CU (128 KiB LDS): makespan quantizes to whole rounds -> grids
// must be multiples of 256 blocks (launch tails separately, split-K).
// grid.z = split-K slices (kbase = z*K), fp32 partials offset z*4096*ldc.
// PROVEN round-4 configuration (141.7us @ 512 blocks) - do not re-schedule.
// ---------------------------------------------------------------------------
#define SA(c) (smem + (c) * 32768)
#define SB(c) (smem + (c) * 32768 + 16384)
#define STGA(c, q, ko) gl2lds16(gA + (size_t)((q) * 64) * lda + (ko), SA(c) + (q) * 4096 + lbase)
#define STGB(c, q, ko) gl2lds16(gB + (size_t)((q) * 64) * ldb + (ko), SB(c) + (q) * 4096 + lbase)

#define PH(mh, kk, READB, STAGES, TAIL)                                          \
  {                                                                              \
    short8 af[4];                                                                \
    _Pragma("unroll")                                                            \
    for (int i_ = 0; i_ < 4; ++i_)                                               \
      af[i_] = *(const short8*)(Ab + (wm * 128 + (mh) * 64 + i_ * 16 + lr) * 64  \
                                + ((((kk) * 4 + lq) ^ (lr & 7)) << 3));          \
    if (READB) {                                                                 \
      _Pragma("unroll")                                                          \
      for (int j_ = 0; j_ < 4; ++j_)                                             \
        bfr[kk][j_] = *(const short8*)(Bb + (wn * 64 + j_ * 16 + lr) * 64        \
                                       + ((((kk) * 4 + lq) ^ (lr & 7)) << 3));   \
    }                                                                            \
    STAGES                                                                       \
    __builtin_amdgcn_sched_barrier(0);                                           \
    __builtin_amdgcn_s_barrier();                                                \
    asm volatile("s_waitcnt lgkmcnt(0)" ::: "memory");                           \
    __builtin_amdgcn_sched_barrier(0);                                           \
    __builtin_amdgcn_s_setprio(1);                                               \
    _Pragma("unroll")                                                            \
    for (int i_ = 0; i_ < 4; ++i_)                                               \
      _Pragma("unroll")                                                          \
      for (int j_ = 0; j_ < 4; ++j_)                                             \
        acc[(mh) * 4 + i_][j_] = __builtin_amdgcn_mfma_f32_16x16x32_bf16(        \
            af[i_], bfr[kk][j_], acc[(mh) * 4 + i_][j_], 0, 0, 0);               \
    __builtin_amdgcn_s_setprio(0);                                               \
    __builtin_amdgcn_sched_barrier(0);                                           \
    TAIL                                                                         \
    __builtin_amdgcn_s_barrier();                                                \
  }

#define TILE(tt, c)                                                              \
  {                                                                              \
    const int t_ = (tt);                                                         \
    const int k1_ = (t_ + 1) << 6, k2_ = (t_ + 2) << 6;                          \
    const bool st1_ = (t_ + 1 < nt), st2_ = (t_ + 2 < nt);                       \
    const u16* Ab = SA(c); const u16* Bb = SB(c);                                \
    PH(0, 0, 1, { if (st1_) { STGA((c) ^ 1, 1, k1_); STGA((c) ^ 1, 3, k1_); } }, {}) \
    PH(1, 0, 0, { if (st1_) { STGB((c) ^ 1, 0, k1_); STGB((c) ^ 1, 1, k1_); } }, {}) \
    PH(0, 1, 1, { if (st1_) { STGB((c) ^ 1, 2, k1_); STGB((c) ^ 1, 3, k1_); } }, {}) \
    PH(1, 1, 0, { if (st2_) { STGA((c), 0, k2_); STGA((c), 2, k2_); } },         \
       { if (t_ < nt - 1) {                                                      \
           if (st2_) { asm volatile("s_waitcnt vmcnt(2)" ::: "memory"); }        \
           else      { asm volatile("s_waitcnt vmcnt(0)" ::: "memory"); } } })   \
  }

template<int OUT_BF16>
__global__ __launch_bounds__(512, 2) void gemm8(
    const u16* __restrict__ A, const u16* __restrict__ Bt, void* __restrict__ Co,
    int K, int lda, int ldb, int ldc, int Nstore)
{
    __shared__ __align__(16) u16 smem[65536];   // [c][A|B] : 2 * (32KB+32KB)
    const int tid  = threadIdx.x;
    const int wave = tid >> 6, lane = tid & 63;
    const int wm = wave >> 2, wn = wave & 3;
    const int lr = lane & 15, lq = lane >> 4;

    // XCD-chunked block swizzle (nwg % 8 == 0 for all our grids)
    const int nbx = gridDim.x;
    const int bid = blockIdx.y * nbx + blockIdx.x;
    const int nwg = nbx * gridDim.y;
    const int cpx = nwg >> 3;
    const int swz = (bid & 7) * cpx + (bid >> 3);
    const int n0 = (swz % nbx) * 256;
    const int m0 = (swz / nbx) * 256;
    const int kbase = blockIdx.z * K;

    // staging: thread -> row (tid>>3) of a 64-row quarter, 16B slot (tid&7);
    // source colblock pre-swizzled so LDS slot s of row r holds colblock s^(r&7)
    const int srow  = tid >> 3;
    const int scb8  = ((tid & 7) ^ (srow & 7)) << 3;
    const int lbase = (tid >> 6) << 9;            // wave*8 rows * 64 u16
    const u16* gA = A  + (size_t)(m0 + srow) * lda + kbase + scb8;
    const u16* gB = Bt + (size_t)(n0 + srow) * ldb + kbase + scb8;

    f32x4 acc[8][4];
    #pragma unroll
    for (int i = 0; i < 8; ++i)
        #pragma unroll
        for (int j = 0; j < 4; ++j) acc[i][j] = (f32x4)0.f;
    short8 bfr[2][4];

    const int nt = K >> 6;

    // prologue: tile0 A+B -> buf0; tile1 A q0,q2 -> buf1; keep 2 in flight
    STGA(0, 0, 0); STGA(0, 1, 0); STGA(0, 2, 0); STGA(0, 3, 0);
    STGB(0, 0, 0); STGB(0, 1, 0); STGB(0, 2, 0); STGB(0, 3, 0);
    STGA(1, 0, 64); STGA(1, 2, 64);
    __builtin_amdgcn_sched_barrier(0);
    asm volatile("s_waitcnt vmcnt(2)" ::: "memory");
    __builtin_amdgcn_sched_barrier(0);
    __builtin_amdgcn_s_barrier();

    for (int t = 0; t < nt; t += 2) {   // nt even (K%128==0)
        TILE(t, 0)
        TILE(t + 1, 1)
    }

    // Epilogue: C/D layout col=lr, row=lq*4+r. Pair lanes (lr, lr^1) to pack
    // two adjacent cols; even lane stores rows lq*4+{0,1}, odd rows +{2,3}.
    const int odd = lr & 1;
    const bool wstore = (n0 + wn * 64) < Nstore;
    #pragma unroll
    for (int i = 0; i < 8; ++i)
        #pragma unroll
        for (int j = 0; j < 4; ++j) {
            float v0 = acc[i][j][0], v1 = acc[i][j][1];
            float v2 = acc[i][j][2], v3 = acc[i][j][3];
            float n0v = __shfl_xor(v0, 1), n1v = __shfl_xor(v1, 1);
            float n2v = __shfl_xor(v2, 1), n3v = __shfl_xor(v3, 1);
            int colb  = n0 + wn * 64 + j * 16 + (lr & ~1);
            int rbase = m0 + wm * 128 + i * 16 + lq * 4 + odd * 2;
            if (wstore) {
                if (OUT_BF16) {
                    u32 w0 = odd ? pack2(n2v, v2) : pack2(v0, n0v);
                    u32 w1 = odd ? pack2(n3v, v3) : pack2(v1, n1v);
                    *(u32*)((u16*)Co + (size_t)rbase * ldc + colb) = w0;
                    *(u32*)((u16*)Co + (size_t)(rbase + 1) * ldc + colb) = w1;
                } else {
                    float* Cf = (float*)Co + (size_t)blockIdx.z * 4096 * ldc;
                    float2 f0 = odd ? make_float2(n2v, v2) : make_float2(v0, n0v);
                    float2 f1 = odd ? make_float2(n3v, v3) : make_float2(v1, n1v);
                    *(float2*)(Cf + (size_t)rbase * ldc + colb) = f0;
                    *(float2*)(Cf + (size_t)(rbase + 1) * ldc + colb) = f1;
                }
            }
        }
}

// ---------------------------------------------------------------------------
// GEMM1 tail combine: xall[row][8192+c] = bf16(sum_z Pt[z][row][c]), c<384.
// Pt: [4][4096][512] f32.
// ---------------------------------------------------------------------------
__global__ __launch_bounds__(256) void tail_add(
    const float* __restrict__ Pt, u16* __restrict__ xall_)
{
    int i = blockIdx.x * 256 + threadIdx.x;      // 4096 rows * 96 col-quads
    int row = i / 96, cq = (i % 96) * 4;
    const float* p = Pt + (size_t)row * NTAILC + cq;
    const size_t zs = (size_t)4096 * NTAILC;
    float4 a = *(const float4*)(p);
    float4 b = *(const float4*)(p + zs);
    float4 c = *(const float4*)(p + 2 * zs);
    float4 d = *(const float4*)(p + 3 * zs);
    ushort4 o;
    o.x = f2bf(a.x + b.x + c.x + d.x);
    o.y = f2bf(a.y + b.y + c.y + d.y);
    o.z = f2bf(a.z + b.z + c.z + d.z);
    o.w = f2bf(a.w + b.w + c.w + d.w);
    *(ushort4*)(xall_ + (size_t)row * XSTR + NMAIN + cq) = o;
}

// ---------------------------------------------------------------------------
// out = a + b (fp32, vectorized)
// ---------------------------------------------------------------------------
__global__ __launch_bounds__(256) void add2_f32(
    const float* __restrict__ a, const float* __restrict__ b,
    float* __restrict__ o, int n4)
{
    int i = blockIdx.x * 256 + threadIdx.x;
    if (i >= n4) return;
    float4 x = ((const float4*)a)[i];
    float4 y = ((const float4*)b)[i];
    x.x += y.x; x.y += y.y; x.z += y.z; x.w += y.w;
    ((float4*)o)[i] = x;
}

// ---------------------------------------------------------------------------
// Causal depthwise conv1d (K=4) + bias + silu, 4 channels/thread, plus the
// dt softplus folded into the otherwise-idle lanes (c4 >= 1088).
// Input = xall cols [4096,8448); dt from cols [8448,8512).
// ---------------------------------------------------------------------------
__global__ __launch_bounds__(256) void conv_kernel(
    const u16* __restrict__ xall, const float* __restrict__ cw,
    const float* __restrict__ cb, u16* __restrict__ xout,
    float* __restrict__ dtb, const float* __restrict__ dt_bias)
{
    int c4 = blockIdx.x * 256 + threadIdx.x;   // 0..1279
    int bt = blockIdx.y;
    if (c4 >= CONV_DIM / 4) {
        int h = c4 - CONV_DIM / 4;             // idle conv lanes -> dt
        if (h < HEADS) {
            float x = bf2f(xall[(size_t)bt * XSTR + INTER + CONV_DIM + h]) + dt_bias[h];
            dtb[bt * HEADS + h] = (x < 10.f) ? log1pf(expf(x)) : x;
        }
        return;
    }
    int c  = c4 * 4;
    int t  = bt & (LSEQ - 1);
    const u16* xi = xall + (size_t)bt * XSTR + INTER + c;
    float4 w0 = *(const float4*)(cw + (size_t)(c + 0) * 4);
    float4 w1 = *(const float4*)(cw + (size_t)(c + 1) * 4);
    float4 w2 = *(const float4*)(cw + (size_t)(c + 2) * 4);
    float4 w3 = *(const float4*)(cw + (size_t)(c + 3) * 4);
    float4 bb = *(const float4*)(cb + c);
    float a0 = bb.x, a1 = bb.y, a2 = bb.z, a3 = bb.w;
    ushort4 x0 = *(const ushort4*)(xi);
    a0 = fmaf(bf2f(x0.x), w0.w, a0); a1 = fmaf(bf2f(x0.y), w1.w, a1);
    a2 = fmaf(bf2f(x0.z), w2.w, a2); a3 = fmaf(bf2f(x0.w), w3.w, a3);
    if (t >= 1) {
        ushort4 xm = *(const ushort4*)(xi - XSTR);
        a0 = fmaf(bf2f(xm.x), w0.z, a0); a1 = fmaf(bf2f(xm.y), w1.z, a1);
        a2 = fmaf(bf2f(xm.z), w2.z, a2); a3 = fmaf(bf2f(xm.w), w3.z, a3);
    }
    if (t >= 2) {
        ushort4 xm = *(const ushort4*)(xi - 2 * XSTR);
        a0 = fmaf(bf2f(xm.x), w0.y, a0); a1 = fmaf(bf2f(xm.y), w1.y, a1);
        a2 = fmaf(bf2f(xm.z), w2.y, a2); a3 = fmaf(bf2f(xm.w), w3.y, a3);
    }
    if (t >= 3) {
        ushort4 xm = *(const ushort4*)(xi - 3 * XSTR);
        a0 = fmaf(bf2f(xm.x), w0.x, a0); a1 = fmaf(bf2f(xm.y), w1.x, a1);
        a2 = fmaf(bf2f(xm.z), w2.x, a2); a3 = fmaf(bf2f(xm.w), w3.x, a3);
    }
    ushort4 o;
    o.x = f2bf(a0 / (1.f + expf(-a0)));
    o.y = f2bf(a1 / (1.f + expf(-a1)));
    o.z = f2bf(a2 / (1.f + expf(-a2)));
    o.w = f2bf(a3 / (1.f + expf(-a3)));
    *(ushort4*)(xout + (size_t)bt * CONV_DIM + c) = o;
}

// ---------------------------------------------------------------------------
// SSD pass 1: T[p][n] = sum_j Xw[j][p] B[j][n], Xw = dt_j e^{cumQ-cum_j} x.
// Global loads vectorized (ushort8); LDS write addresses unchanged.
// ---------------------------------------------------------------------------
__global__ __launch_bounds__(256) void ssd_chunk_state(
    const u16* __restrict__ xc, const float* __restrict__ dtb,
    const float* __restrict__ A_log,
    u16* __restrict__ Tg, float* __restrict__ decayQ)
{
    const int bid = blockIdx.x;
    const int b = bid >> 11, h = (bid >> 5) & 63, c = bid & 31;
    const int t0 = c * QCH;
    const int tid = threadIdx.x;
    const int wave = tid >> 6, lane = tid & 63;
    const int lr = lane & 15, lq = lane >> 4;

    __shared__ __align__(16) u16 BT[128][72];   // B^T: [n][j]
    __shared__ __align__(16) u16 XwT[64][72];   // Xw^T: [p][j]
    __shared__ float sclL[QCH];

    const u16* xg = xc + (size_t)b * LSEQ * CONV_DIM;

    if (tid < 64) {
        float dtv = dtb[((size_t)b * LSEQ + t0 + tid) * HEADS + h];
        float a = -dtv * expf(A_log[h]);
        float s = a;
        #pragma unroll
        for (int off = 1; off < 64; off <<= 1) {
            float o = __shfl_up(s, off, 64);
            if (tid >= off) s += o;
        }
        float cq = __shfl(s, 63, 64);
        sclL[tid] = dtv * expf(cq - s);
        if (tid == 0) decayQ[((b * 64 + h) << 5) + c] = expf(cq);
    }
    __syncthreads();

    #pragma unroll
    for (int r = 0; r < 2; ++r) {
        int idx = tid + 256 * r;                // 512 items: (j, p8)
        int j = idx >> 3, p8 = (idx & 7) * 8;
        us8 xv = *(const us8*)(xg + (size_t)(t0 + j) * CONV_DIM + h * 64 + p8);
        float scl = sclL[j];
        #pragma unroll
        for (int k = 0; k < 8; ++k)
            XwT[p8 + k][j] = f2bf(bf2f(xv[k]) * scl);
    }
    #pragma unroll
    for (int r = 0; r < 4; ++r) {
        int idx = tid + 256 * r;                // 1024 items: (j, n8)
        int j = idx >> 4, n8 = (idx & 15) * 8;
        us8 bv = *(const us8*)(xg + (size_t)(t0 + j) * CONV_DIM + INTER + n8);
        #pragma unroll
        for (int k = 0; k < 8; ++k)
            BT[n8 + k][j] = bv[k];
    }
    __syncthreads();

    f32x4 acc[8];
    #pragma unroll
    for (int i = 0; i < 8; ++i) acc[i] = (f32x4)0.f;
    #pragma unroll
    for (int k0 = 0; k0 < QCH; k0 += 32) {
        short8 af = *(const short8*)&XwT[wave * 16 + lr][k0 + lq * 8];
        #pragma unroll
        for (int nt = 0; nt < 8; ++nt) {
            short8 bfr = *(const short8*)&BT[nt * 16 + lr][k0 + lq * 8];
            acc[nt] = __builtin_amdgcn_mfma_f32_16x16x32_bf16(af, bfr, acc[nt], 0, 0, 0);
        }
    }
    u16* To = Tg + ((((size_t)(b * 64 + h)) * NCHUNK + c) * 64) * 128;
    #pragma unroll
    for (int nt = 0; nt < 8; ++nt)
        #pragma unroll
        for (int r = 0; r < 4; ++r)
            To[(wave * 16 + lq * 4 + r) * 128 + nt * 16 + lr] = f2bf(acc[nt][r]);
}

// ---------------------------------------------------------------------------
// SSD pass 2: sequential recurrence over chunk states (in-place).
// 512 blocks: (bh, n-quarter); each thread owns (p, 8 n-elems).
// ---------------------------------------------------------------------------
__global__ __launch_bounds__(256) void ssd_state_scan(
    u16* __restrict__ Tg, const float* __restrict__ decayQ)
{
    const int bh = blockIdx.x >> 2, nq = blockIdx.x & 3;
    const int tid = threadIdx.x;
    const int p = tid >> 2, nb = nq * 32 + (tid & 3) * 8;
    float S[8];
    #pragma unroll
    for (int m = 0; m < 8; ++m) S[m] = 0.f;

    for (int c = 0; c < NCHUNK; ++c) {
        u16* base = Tg + ((((size_t)bh * NCHUNK + c) * 64 + p) * 128) + nb;
        uint4 tv = *(const uint4*)base;
        uint4 sv;
        sv.x = pack2(S[0], S[1]);
        sv.y = pack2(S[2], S[3]);
        sv.z = pack2(S[4], S[5]);
        sv.w = pack2(S[6], S[7]);
        *(uint4*)base = sv;
        float dq = decayQ[(bh << 5) + c];
        const u32* w = (const u32*)&tv;
        #pragma unroll
        for (int e = 0; e < 4; ++e) {
            S[e*2]     = fmaf(dq, S[e*2],     bf2f((u16)(w[e] & 0xffffu)));
            S[e*2 + 1] = fmaf(dq, S[e*2 + 1], bf2f((u16)(w[e] >> 16)));
        }
    }
}

// ---------------------------------------------------------------------------
// SSD pass 3: Y = (C·B^T ∘ M)·X + diag(e^{cum})·(C·S_prev^T) + D·x.
// y written strided (XSTR) into the dead xBC region of xall.
// XT global loads vectorized (ushort8); LDS writes unchanged.
// ---------------------------------------------------------------------------
__global__ __launch_bounds__(256) void ssd_output(
    const u16* __restrict__ xc, const float* __restrict__ dtb,
    const float* __restrict__ A_log, const float* __restrict__ Dvec,
    const u16* __restrict__ Sg,
    u16* __restrict__ y)           // base xall+4096, row stride XSTR
{
    const int bid = blockIdx.x;
    const int b = bid >> 11, h = (bid >> 5) & 63, c = bid & 31;
    const int t0 = c * QCH;
    const int tid = threadIdx.x;
    const int wave = tid >> 6, lane = tid & 63;
    const int lr = lane & 15, lq = lane >> 4;

    __shared__ __align__(16) u16 C_lds[64][136];
    __shared__ __align__(16) u16 B_lds[64][136];
    __shared__ __align__(16) u16 S_lds[64][136];
    __shared__ __align__(16) u16 P_lds[64][72];
    __shared__ __align__(16) u16 XT[64][72];
    __shared__ float cumL[QCH], dtsL[QCH], escL[QCH];

    const u16* xg = xc + (size_t)b * LSEQ * CONV_DIM;

    if (tid < 64) {
        float dtv = dtb[((size_t)b * LSEQ + t0 + tid) * HEADS + h];
        float a = -dtv * expf(A_log[h]);
        float s = a;
        #pragma unroll
        for (int off = 1; off < 64; off <<= 1) {
            float o = __shfl_up(s, off, 64);
            if (tid >= off) s += o;
        }
        cumL[tid] = s;
        dtsL[tid] = dtv;
        escL[tid] = expf(s);
    }
    #pragma unroll
    for (int r4 = 0; r4 < 4; ++r4) {
        int idx4 = tid + 256 * r4;
        int j = idx4 >> 4, c8 = (idx4 & 15) * 8;
        *(uint4*)&B_lds[j][c8] = *(const uint4*)(xg + (size_t)(t0 + j) * CONV_DIM + INTER + c8);
        *(uint4*)&C_lds[j][c8] = *(const uint4*)(xg + (size_t)(t0 + j) * CONV_DIM + INTER + NSTATE + c8);
        *(uint4*)&S_lds[j][c8] = *(const uint4*)(Sg + ((((size_t)(b * 64 + h)) * NCHUNK + c) * 64 + j) * 128 + c8);
    }
    #pragma unroll
    for (int r = 0; r < 2; ++r) {
        int idx = tid + 256 * r;                // 512 items: (j, p8)
        int j = idx >> 3, p8 = (idx & 7) * 8;
        us8 xv = *(const us8*)(xg + (size_t)(t0 + j) * CONV_DIM + h * 64 + p8);
        #pragma unroll
        for (int k = 0; k < 8; ++k)
            XT[p8 + k][j] = xv[k];
    }
    __syncthreads();

    f32x4 accG[4];
    #pragma unroll
    for (int i = 0; i < 4; ++i) accG[i] = (f32x4)0.f;
    #pragma unroll
    for (int k0 = 0; k0 < NSTATE; k0 += 32) {
        short8 af = *(const short8*)&C_lds[wave * 16 + lr][k0 + lq * 8];
        #pragma unroll
        for (int jt = 0; jt < 4; ++jt) {
            short8 bfr = *(const short8*)&B_lds[jt * 16 + lr][k0 + lq * 8];
            accG[jt] = __builtin_amdgcn_mfma_f32_16x16x32_bf16(af, bfr, accG[jt], 0, 0, 0);
        }
    }
    #pragma unroll
    for (int jt = 0; jt < 4; ++jt)
        #pragma unroll
        for (int r = 0; r < 4; ++r) {
            int ii = wave * 16 + lq * 4 + r;
            int jj = jt * 16 + lr;
            float v = (jj <= ii)
                ? accG[jt][r] * dtsL[jj] * expf(cumL[ii] - cumL[jj]) : 0.f;
            P_lds[ii][jj] = f2bf(v);
        }
    __syncthreads();

    f32x4 accY[4], accZ[4];
    #pragma unroll
    for (int i = 0; i < 4; ++i) { accY[i] = (f32x4)0.f; accZ[i] = (f32x4)0.f; }
    #pragma unroll
    for (int k0 = 0; k0 < QCH; k0 += 32) {
        short8 af = *(const short8*)&P_lds[wave * 16 + lr][k0 + lq * 8];
        #pragma unroll
        for (int pt = 0; pt < 4; ++pt) {
            short8 bfr = *(const short8*)&XT[pt * 16 + lr][k0 + lq * 8];
            accY[pt] = __builtin_amdgcn_mfma_f32_16x16x32_bf16(af, bfr, accY[pt], 0, 0, 0);
        }
    }
    #pragma unroll
    for (int k0 = 0; k0 < NSTATE; k0 += 32) {
        short8 af = *(const short8*)&C_lds[wave * 16 + lr][k0 + lq * 8];
        #pragma unroll
        for (int pt = 0; pt < 4; ++pt) {
            short8 bfr = *(const short8*)&S_lds[pt * 16 + lr][k0 + lq * 8];
            accZ[pt] = __builtin_amdgcn_mfma_f32_16x16x32_bf16(af, bfr, accZ[pt], 0, 0, 0);
        }
    }

    const float Dh = Dvec[h];
    u16* yg = y + ((size_t)b * LSEQ + t0) * XSTR + h * 64;
    #pragma unroll
    for (int pt = 0; pt < 4; ++pt)
        #pragma unroll
        for (int r = 0; r < 4; ++r) {
            int ii = wave * 16 + lq * 4 + r;
            int pp = pt * 16 + lr;
            float xv = bf2f(XT[pp][ii]);
            float o = accY[pt][r] + escL[ii] * accZ[pt][r] + Dh * xv;
            yg[(size_t)ii * XSTR + pp] = f2bf(o);
        }
}

// ---------------------------------------------------------------------------
// Gated RMSNorm (G=1). y = xall cols [4096,8192), gate = cols [0,4096);
// normed bf16 written in-place over gate. Row stride XSTR. Vectorized 8/lane.
// ---------------------------------------------------------------------------
__global__ __launch_bounds__(256) void norm_kernel(
    u16* __restrict__ xall, const float* __restrict__ w)
{
    const int row = blockIdx.x;
    const u16* yr = xall + (size_t)row * XSTR + INTER;
    u16*       gr = xall + (size_t)row * XSTR;
    const int tid = threadIdx.x;

    float v[16];
    float ss = 0.f;
    #pragma unroll
    for (int i = 0; i < 2; ++i) {
        int e0 = i * 2048 + tid * 8;
        uint4 hv4 = *(const uint4*)(yr + e0);
        uint4 gv4 = *(const uint4*)(gr + e0);
        const u16* hp = (const u16*)&hv4;
        const u16* gp = (const u16*)&gv4;
        #pragma unroll
        for (int k = 0; k < 8; ++k) {
            float hv = bf2f(hp[k]);
            float g  = bf2f(gp[k]);
            float val = hv * (g / (1.f + expf(-g)));
            v[i * 8 + k] = val;
            ss = fmaf(val, val, ss);
        }
    }
    #pragma unroll
    for (int o = 32; o > 0; o >>= 1) ss += __shfl_xor(ss, o);
    __shared__ float part[4];
    if ((tid & 63) == 0) part[tid >> 6] = ss;
    __syncthreads();
    float tot  = part[0] + part[1] + part[2] + part[3];
    float rinv = rsqrtf(tot * (1.f / INTER) + EPS);
    #pragma unroll
    for (int i = 0; i < 2; ++i) {
        int e0 = i * 2048 + tid * 8;
        float4 wa = *(const float4*)(w + e0);
        float4 wb = *(const float4*)(w + e0 + 4);
        uint4 sv;
        sv.x = pack2(wa.x * v[i*8+0] * rinv, wa.y * v[i*8+1] * rinv);
        sv.y = pack2(wa.z * v[i*8+2] * rinv, wa.w * v[i*8+3] * rinv);
        sv.z = pack2(wb.x * v[i*8+4] * rinv, wb.y * v[i*8+5] * rinv);
        sv.w = pack2(wb.z * v[i*8+6] * rinv, wb.w * v[i*8+7] * rinv);
        *(uint4*)(gr + e0) = sv;
    }
}

// ---------------------------------------------------------------------------
extern "C" void kernel_launch(void* const* d_in, const int* in_sizes, int n_in,
                              void* d_out, int out_size, void* d_ws, size_t ws_size,
                              hipStream_t stream)
{
    const float* hs      = (const float*)d_in[0];
    const float* W_z     = (const float*)d_in[1];
    const float* W_xBC   = (const float*)d_in[2];
    const float* W_dt    = (const float*)d_in[3];
    const float* conv_w  = (const float*)d_in[4];
    const float* conv_b  = (const float*)d_in[5];
    const float* dt_bias = (const float*)d_in[6];
    const float* A_log   = (const float*)d_in[7];
    const float* Dv      = (const float*)d_in[8];
    const float* norm_w  = (const float*)d_in[9];
    const float* W_out   = (const float*)d_in[10];
    float* out = (float*)d_out;
    char*  w8  = (char*)d_ws;

    // workspace (bytes):
    u16* hs_bf  = (u16*)(w8 + 0);            // 16,777,216
    u16* Wt_all = (u16*)(w8 + 16777216);     // 8704*2048*2 = 35,651,584 (ends 52,428,800)
    u16* Tbuf   = (u16*)(w8 + 0);            // 67,108,864 (alias hs_bf+Wt_all; SSD phase)
    float* Cpart= (float*)(w8 + 0);          // 2*4096*2048*4 = 67,108,864 (alias; GEMM2 phase)
    u16* Wt_out = (u16*)(w8 + 67108864);     // 16,777,216
    u16* xall   = (u16*)(w8 + 83886080);     // 4096*8576*2 = 70,254,592 (ends 154,140,672)
    u16* xconv  = (u16*)(w8 + 154140672);    // 35,651,584
    float* Ptail= (float*)(w8 + 154140672);  // 4*4096*512*4 = 33,554,432 (alias xconv; dead before conv)
    float* dtb  = (float*)(w8 + 189792256);  // 1,048,576
    float* dcq  = (float*)(w8 + 190840832);  // 16,384 (total 190,857,216)

    const int M = B_SZ * LSEQ;               // 4096

    cvt_f32_bf16<<<(M * DMODEL / 4 + 255) / 256, 256, 0, stream>>>(hs, hs_bf, M * DMODEL / 4);
    // Wt_all rows: [0,4096) = W_z^T, [4096,8448) = W_xBC^T, [8448,8512) = W_dt^T,
    // [8512,8704) = zero pad (tail launch computes cols up to 8704, stores <8576)
    tr_f32_bf16<<<dim3(INTER / 64,    DMODEL / 64), 256, 0, stream>>>(W_z,   Wt_all, DMODEL, INTER);
    tr_f32_bf16<<<dim3(CONV_DIM / 64, DMODEL / 64), 256, 0, stream>>>(W_xBC, Wt_all + (size_t)INTER * DMODEL, DMODEL, CONV_DIM);
    tr_f32_bf16<<<dim3(1,             DMODEL / 64), 256, 0, stream>>>(W_dt,  Wt_all + (size_t)(INTER + CONV_DIM) * DMODEL, DMODEL, 64);
    hipMemsetAsync(Wt_all + (size_t)(INTER + CONV_DIM + 64) * DMODEL, 0, (size_t)192 * DMODEL * 2, stream);
    tr_f32_bf16<<<dim3(DMODEL / 64,   INTER / 64),  256, 0, stream>>>(W_out, Wt_out, INTER, DMODEL);

    // GEMM1 main: cols [0,8192) -> 512 blocks = exactly 2 rounds @ 1 block/CU
    gemm8<1><<<dim3(NMAIN / 256, M / 256, 1), 512, 0, stream>>>(
        hs_bf, Wt_all, (void*)xall, DMODEL /*K*/, DMODEL, DMODEL,
        XSTR /*ldc*/, NMAIN /*Nstore: all*/);
    // GEMM1 tail: cols [8192,8704), split-K=4 -> 128 blocks (K=512 each)
    gemm8<0><<<dim3(NTAILC / 256, M / 256, 4), 512, 0, stream>>>(
        hs_bf, Wt_all + (size_t)NMAIN * DMODEL, (void*)Ptail, DMODEL / 4 /*K*/,
        DMODEL, DMODEL, NTAILC /*ldc*/, NTAILS /*Nstore*/);
    tail_add<<<M * (NTAILS / 4) / 256, 256, 0, stream>>>(Ptail, xall);

    // conv (with dt folded into idle lanes)
    conv_kernel<<<dim3((CONV_DIM / 4 + 255) / 256, M), 256, 0, stream>>>(
        xall, conv_w, conv_b, xconv, dtb, dt_bias);

    ssd_chunk_state<<<B_SZ * HEADS * NCHUNK, 256, 0, stream>>>(xconv, dtb, A_log, Tbuf, dcq);
    ssd_state_scan<<<B_SZ * HEADS * 4, 256, 0, stream>>>(Tbuf, dcq);
    ssd_output<<<B_SZ * HEADS * NCHUNK, 256, 0, stream>>>(xconv, dtb, A_log, Dv, Tbuf, xall + INTER);

    norm_kernel<<<M, 256, 0, stream>>>(xall, norm_w);

    // out GEMM: split-K=2 over gridDim.z (256 blocks = 1 round), fp32 partials
    gemm8<0><<<dim3(DMODEL / 256, M / 256, 2), 512, 0, stream>>>(
        xall, Wt_out, (void*)Cpart, INTER / 2 /*K per split*/, XSTR /*lda*/,
        INTER /*ldb*/, DMODEL /*ldc*/, DMODEL /*Nstore*/);
    add2_f32<<<(M * DMODEL / 4 + 255) / 256, 256, 0, stream>>>(
        Cpart, Cpart + (size_t)M * DMODEL, out, M * DMODEL / 4);
}

// Round 8
// 607.556 us; speedup vs baseline: 2.5073x; 1.0387x over previous
//
#include <hip/hip_runtime.h>
#include <hip/hip_bf16.h>
#include <math.h>

typedef unsigned short u16;
typedef unsigned int   u32;
typedef __attribute__((ext_vector_type(8))) short short8;
typedef __attribute__((ext_vector_type(4))) float f32x4;

#define B_SZ     2
#define LSEQ     2048
#define DMODEL   2048
#define INTER    4096
#define HEADS    64
#define NSTATE   128
#define CONV_DIM 4352            /* INTER + 2*128 */
#define XSTR     8576            /* xall row stride: 4096 gate + 4480 xBC/dt */
#define NMAIN    8192            /* GEMM1 main launch cols [0,8192) */
#define NTAILC   512             /* GEMM1 tail compute cols [8192,8704) */
#define NTAILS   384             /* tail stored cols (8192..8576) */
#define EPS      1e-5f
#define QCH      64              /* SSD chunk length */
#define NCHUNK   (LSEQ / QCH)    /* 32 */

__device__ __forceinline__ float bf2f(u16 u) {
    u32 v = ((u32)u) << 16;
    return __builtin_bit_cast(float, v);
}
__device__ __forceinline__ u16 f2bf(float x) {
    __hip_bfloat16 h = __float2bfloat16(x);   // RNE
    return __builtin_bit_cast(u16, h);
}
__device__ __forceinline__ u32 pack2(float lo, float hi) {
    return (u32)f2bf(lo) | ((u32)f2bf(hi) << 16);
}
__device__ __forceinline__ void gl2lds16(const void* g, void* l) {
    __builtin_amdgcn_global_load_lds(
        (const __attribute__((address_space(1))) u32*)g,
        (__attribute__((address_space(3))) u32*)l, 16, 0, 0);
}

// ---------------------------------------------------------------------------
// fp32 -> bf16 elementwise (n4 = count/4)
// ---------------------------------------------------------------------------
__global__ __launch_bounds__(256) void cvt_f32_bf16(
    const float* __restrict__ in, u16* __restrict__ out, int n4)
{
    int i = blockIdx.x * 256 + threadIdx.x;
    if (i >= n4) return;
    float4 v = ((const float4*)in)[i];
    ushort4 o;
    o.x = f2bf(v.x); o.y = f2bf(v.y); o.z = f2bf(v.z); o.w = f2bf(v.w);
    ((ushort4*)out)[i] = o;
}

// ---------------------------------------------------------------------------
// Transpose + convert: in fp32 [R][C] -> out bf16 [C][R]. R,C multiples of 64.
// ---------------------------------------------------------------------------
__global__ __launch_bounds__(256) void tr_f32_bf16(
    const float* __restrict__ in, u16* __restrict__ out, int R, int C)
{
    __shared__ u16 tile[64][68];
    const int r0 = blockIdx.y * 64, c0 = blockIdx.x * 64;
    const int tr = threadIdx.x >> 4, tc = (threadIdx.x & 15) * 4;
    #pragma unroll
    for (int i = 0; i < 4; ++i) {
        int r = tr + i * 16;
        float4 v = *(const float4*)(in + (size_t)(r0 + r) * C + c0 + tc);
        tile[r][tc + 0] = f2bf(v.x);
        tile[r][tc + 1] = f2bf(v.y);
        tile[r][tc + 2] = f2bf(v.z);
        tile[r][tc + 3] = f2bf(v.w);
    }
    __syncthreads();
    #pragma unroll
    for (int i = 0; i < 4; ++i) {
        int oc = tr + i * 16;
        ushort4 o;
        o.x = tile[tc + 0][oc];
        o.y = tile[tc + 1][oc];
        o.z = tile[tc + 2][oc];
        o.w = tile[tc + 3][oc];
        *(ushort4*)(out + (size_t)(c0 + oc) * R + r0 + tc) = o;
    }
}

// ---------------------------------------------------------------------------
// 256x256 8-phase bf16 MFMA GEMM, NT form: C[M,N] = A[M,K](lda) @ Bt[N,K](ldb)^T
// PROVEN round-4 configuration (141.7us @ 512 blocks) - do not re-schedule.
// ---------------------------------------------------------------------------
#define SA(c) (smem + (c) * 32768)
#define SB(c) (smem + (c) * 32768 + 16384)
#define STGA(c, q, ko) gl2lds16(gA + (size_t)((q) * 64) * lda + (ko), SA(c) + (q) * 4096 + lbase)
#define STGB(c, q, ko) gl2lds16(gB + (size_t)((q) * 64) * ldb + (ko), SB(c) + (q) * 4096 + lbase)

#define PH(mh, kk, READB, STAGES, TAIL)                                          \
  {                                                                              \
    short8 af[4];                                                                \
    _Pragma("unroll")                                                            \
    for (int i_ = 0; i_ < 4; ++i_)                                               \
      af[i_] = *(const short8*)(Ab + (wm * 128 + (mh) * 64 + i_ * 16 + lr) * 64  \
                                + ((((kk) * 4 + lq) ^ (lr & 7)) << 3));          \
    if (READB) {                                                                 \
      _Pragma("unroll")                                                          \
      for (int j_ = 0; j_ < 4; ++j_)                                             \
        bfr[kk][j_] = *(const short8*)(Bb + (wn * 64 + j_ * 16 + lr) * 64        \
                                       + ((((kk) * 4 + lq) ^ (lr & 7)) << 3));   \
    }                                                                            \
    STAGES                                                                       \
    __builtin_amdgcn_sched_barrier(0);                                           \
    __builtin_amdgcn_s_barrier();                                                \
    asm volatile("s_waitcnt lgkmcnt(0)" ::: "memory");                           \
    __builtin_amdgcn_sched_barrier(0);                                           \
    __builtin_amdgcn_s_setprio(1);                                               \
    _Pragma("unroll")                                                            \
    for (int i_ = 0; i_ < 4; ++i_)                                               \
      _Pragma("unroll")                                                          \
      for (int j_ = 0; j_ < 4; ++j_)                                             \
        acc[(mh) * 4 + i_][j_] = __builtin_amdgcn_mfma_f32_16x16x32_bf16(        \
            af[i_], bfr[kk][j_], acc[(mh) * 4 + i_][j_], 0, 0, 0);               \
    __builtin_amdgcn_s_setprio(0);                                               \
    __builtin_amdgcn_sched_barrier(0);                                           \
    TAIL                                                                         \
    __builtin_amdgcn_s_barrier();                                                \
  }

#define TILE(tt, c)                                                              \
  {                                                                              \
    const int t_ = (tt);                                                         \
    const int k1_ = (t_ + 1) << 6, k2_ = (t_ + 2) << 6;                          \
    const bool st1_ = (t_ + 1 < nt), st2_ = (t_ + 2 < nt);                       \
    const u16* Ab = SA(c); const u16* Bb = SB(c);                                \
    PH(0, 0, 1, { if (st1_) { STGA((c) ^ 1, 1, k1_); STGA((c) ^ 1, 3, k1_); } }, {}) \
    PH(1, 0, 0, { if (st1_) { STGB((c) ^ 1, 0, k1_); STGB((c) ^ 1, 1, k1_); } }, {}) \
    PH(0, 1, 1, { if (st1_) { STGB((c) ^ 1, 2, k1_); STGB((c) ^ 1, 3, k1_); } }, {}) \
    PH(1, 1, 0, { if (st2_) { STGA((c), 0, k2_); STGA((c), 2, k2_); } },         \
       { if (t_ < nt - 1) {                                                      \
           if (st2_) { asm volatile("s_waitcnt vmcnt(2)" ::: "memory"); }        \
           else      { asm volatile("s_waitcnt vmcnt(0)" ::: "memory"); } } })   \
  }

template<int OUT_BF16>
__global__ __launch_bounds__(512, 2) void gemm8(
    const u16* __restrict__ A, const u16* __restrict__ Bt, void* __restrict__ Co,
    int K, int lda, int ldb, int ldc, int Nstore)
{
    __shared__ __align__(16) u16 smem[65536];   // [c][A|B] : 2 * (32KB+32KB)
    const int tid  = threadIdx.x;
    const int wave = tid >> 6, lane = tid & 63;
    const int wm = wave >> 2, wn = wave & 3;
    const int lr = lane & 15, lq = lane >> 4;

    // XCD-chunked block swizzle (nwg % 8 == 0 for all our grids)
    const int nbx = gridDim.x;
    const int bid = blockIdx.y * nbx + blockIdx.x;
    const int nwg = nbx * gridDim.y;
    const int cpx = nwg >> 3;
    const int swz = (bid & 7) * cpx + (bid >> 3);
    const int n0 = (swz % nbx) * 256;
    const int m0 = (swz / nbx) * 256;
    const int kbase = blockIdx.z * K;

    // staging: thread -> row (tid>>3) of a 64-row quarter, 16B slot (tid&7);
    // source colblock pre-swizzled so LDS slot s of row r holds colblock s^(r&7)
    const int srow  = tid >> 3;
    const int scb8  = ((tid & 7) ^ (srow & 7)) << 3;
    const int lbase = (tid >> 6) << 9;            // wave*8 rows * 64 u16
    const u16* gA = A  + (size_t)(m0 + srow) * lda + kbase + scb8;
    const u16* gB = Bt + (size_t)(n0 + srow) * ldb + kbase + scb8;

    f32x4 acc[8][4];
    #pragma unroll
    for (int i = 0; i < 8; ++i)
        #pragma unroll
        for (int j = 0; j < 4; ++j) acc[i][j] = (f32x4)0.f;
    short8 bfr[2][4];

    const int nt = K >> 6;

    // prologue: tile0 A+B -> buf0; tile1 A q0,q2 -> buf1; keep 2 in flight
    STGA(0, 0, 0); STGA(0, 1, 0); STGA(0, 2, 0); STGA(0, 3, 0);
    STGB(0, 0, 0); STGB(0, 1, 0); STGB(0, 2, 0); STGB(0, 3, 0);
    STGA(1, 0, 64); STGA(1, 2, 64);
    __builtin_amdgcn_sched_barrier(0);
    asm volatile("s_waitcnt vmcnt(2)" ::: "memory");
    __builtin_amdgcn_sched_barrier(0);
    __builtin_amdgcn_s_barrier();

    for (int t = 0; t < nt; t += 2) {   // nt even (K%128==0)
        TILE(t, 0)
        TILE(t + 1, 1)
    }

    // Epilogue: C/D layout col=lr, row=lq*4+r. Pair lanes (lr, lr^1) to pack
    // two adjacent cols; even lane stores rows lq*4+{0,1}, odd rows +{2,3}.
    const int odd = lr & 1;
    const bool wstore = (n0 + wn * 64) < Nstore;
    #pragma unroll
    for (int i = 0; i < 8; ++i)
        #pragma unroll
        for (int j = 0; j < 4; ++j) {
            float v0 = acc[i][j][0], v1 = acc[i][j][1];
            float v2 = acc[i][j][2], v3 = acc[i][j][3];
            float n0v = __shfl_xor(v0, 1), n1v = __shfl_xor(v1, 1);
            float n2v = __shfl_xor(v2, 1), n3v = __shfl_xor(v3, 1);
            int colb  = n0 + wn * 64 + j * 16 + (lr & ~1);
            int rbase = m0 + wm * 128 + i * 16 + lq * 4 + odd * 2;
            if (wstore) {
                if (OUT_BF16) {
                    u32 w0 = odd ? pack2(n2v, v2) : pack2(v0, n0v);
                    u32 w1 = odd ? pack2(n3v, v3) : pack2(v1, n1v);
                    *(u32*)((u16*)Co + (size_t)rbase * ldc + colb) = w0;
                    *(u32*)((u16*)Co + (size_t)(rbase + 1) * ldc + colb) = w1;
                } else {
                    float* Cf = (float*)Co + (size_t)blockIdx.z * 4096 * ldc;
                    float2 f0 = odd ? make_float2(n2v, v2) : make_float2(v0, n0v);
                    float2 f1 = odd ? make_float2(n3v, v3) : make_float2(v1, n1v);
                    *(float2*)(Cf + (size_t)rbase * ldc + colb) = f0;
                    *(float2*)(Cf + (size_t)(rbase + 1) * ldc + colb) = f1;
                }
            }
        }
}

// ---------------------------------------------------------------------------
// GEMM1 tail combine: xall[row][8192+c] = bf16(sum_z Pt[z][row][c]), c<384.
// Pt: [4][4096][512] f32.
// ---------------------------------------------------------------------------
__global__ __launch_bounds__(256) void tail_add(
    const float* __restrict__ Pt, u16* __restrict__ xall_)
{
    int i = blockIdx.x * 256 + threadIdx.x;      // 4096 rows * 96 col-quads
    int row = i / 96, cq = (i % 96) * 4;
    const float* p = Pt + (size_t)row * NTAILC + cq;
    const size_t zs = (size_t)4096 * NTAILC;
    float4 a = *(const float4*)(p);
    float4 b = *(const float4*)(p + zs);
    float4 c = *(const float4*)(p + 2 * zs);
    float4 d = *(const float4*)(p + 3 * zs);
    ushort4 o;
    o.x = f2bf(a.x + b.x + c.x + d.x);
    o.y = f2bf(a.y + b.y + c.y + d.y);
    o.z = f2bf(a.z + b.z + c.z + d.z);
    o.w = f2bf(a.w + b.w + c.w + d.w);
    *(ushort4*)(xall_ + (size_t)row * XSTR + NMAIN + cq) = o;
}

// ---------------------------------------------------------------------------
// out = a + b (fp32, vectorized)
// ---------------------------------------------------------------------------
__global__ __launch_bounds__(256) void add2_f32(
    const float* __restrict__ a, const float* __restrict__ b,
    float* __restrict__ o, int n4)
{
    int i = blockIdx.x * 256 + threadIdx.x;
    if (i >= n4) return;
    float4 x = ((const float4*)a)[i];
    float4 y = ((const float4*)b)[i];
    x.x += y.x; x.y += y.y; x.z += y.z; x.w += y.w;
    ((float4*)o)[i] = x;
}

// ---------------------------------------------------------------------------
// Causal depthwise conv1d (K=4) + bias + silu, 4 channels/thread, plus the
// dt softplus folded into the otherwise-idle lanes (c4 >= 1088).
// ---------------------------------------------------------------------------
__global__ __launch_bounds__(256) void conv_kernel(
    const u16* __restrict__ xall, const float* __restrict__ cw,
    const float* __restrict__ cb, u16* __restrict__ xout,
    float* __restrict__ dtb, const float* __restrict__ dt_bias)
{
    int c4 = blockIdx.x * 256 + threadIdx.x;   // 0..1279
    int bt = blockIdx.y;
    if (c4 >= CONV_DIM / 4) {
        int h = c4 - CONV_DIM / 4;             // idle conv lanes -> dt
        if (h < HEADS) {
            float x = bf2f(xall[(size_t)bt * XSTR + INTER + CONV_DIM + h]) + dt_bias[h];
            dtb[bt * HEADS + h] = (x < 10.f) ? log1pf(expf(x)) : x;
        }
        return;
    }
    int c  = c4 * 4;
    int t  = bt & (LSEQ - 1);
    const u16* xi = xall + (size_t)bt * XSTR + INTER + c;
    float4 w0 = *(const float4*)(cw + (size_t)(c + 0) * 4);
    float4 w1 = *(const float4*)(cw + (size_t)(c + 1) * 4);
    float4 w2 = *(const float4*)(cw + (size_t)(c + 2) * 4);
    float4 w3 = *(const float4*)(cw + (size_t)(c + 3) * 4);
    float4 bb = *(const float4*)(cb + c);
    float a0 = bb.x, a1 = bb.y, a2 = bb.z, a3 = bb.w;
    ushort4 x0 = *(const ushort4*)(xi);
    a0 = fmaf(bf2f(x0.x), w0.w, a0); a1 = fmaf(bf2f(x0.y), w1.w, a1);
    a2 = fmaf(bf2f(x0.z), w2.w, a2); a3 = fmaf(bf2f(x0.w), w3.w, a3);
    if (t >= 1) {
        ushort4 xm = *(const ushort4*)(xi - XSTR);
        a0 = fmaf(bf2f(xm.x), w0.z, a0); a1 = fmaf(bf2f(xm.y), w1.z, a1);
        a2 = fmaf(bf2f(xm.z), w2.z, a2); a3 = fmaf(bf2f(xm.w), w3.z, a3);
    }
    if (t >= 2) {
        ushort4 xm = *(const ushort4*)(xi - 2 * XSTR);
        a0 = fmaf(bf2f(xm.x), w0.y, a0); a1 = fmaf(bf2f(xm.y), w1.y, a1);
        a2 = fmaf(bf2f(xm.z), w2.y, a2); a3 = fmaf(bf2f(xm.w), w3.y, a3);
    }
    if (t >= 3) {
        ushort4 xm = *(const ushort4*)(xi - 3 * XSTR);
        a0 = fmaf(bf2f(xm.x), w0.x, a0); a1 = fmaf(bf2f(xm.y), w1.x, a1);
        a2 = fmaf(bf2f(xm.z), w2.x, a2); a3 = fmaf(bf2f(xm.w), w3.x, a3);
    }
    ushort4 o;
    o.x = f2bf(a0 / (1.f + expf(-a0)));
    o.y = f2bf(a1 / (1.f + expf(-a1)));
    o.z = f2bf(a2 / (1.f + expf(-a2)));
    o.w = f2bf(a3 / (1.f + expf(-a3)));
    *(ushort4*)(xout + (size_t)bt * CONV_DIM + c) = o;
}

// ---------------------------------------------------------------------------
// SSD pass 1: T[p][n] = sum_j Xw[j][p] B[j][n], Xw = dt_j e^{cumQ-cum_j} x.
// Round-4 staging (proven); NEW pack2-paired u32 store epilogue.
// ---------------------------------------------------------------------------
__global__ __launch_bounds__(256) void ssd_chunk_state(
    const u16* __restrict__ xc, const float* __restrict__ dtb,
    const float* __restrict__ A_log,
    u16* __restrict__ Tg, float* __restrict__ decayQ)
{
    const int bid = blockIdx.x;
    const int b = bid >> 11, h = (bid >> 5) & 63, c = bid & 31;
    const int t0 = c * QCH;
    const int tid = threadIdx.x;
    const int wave = tid >> 6, lane = tid & 63;
    const int lr = lane & 15, lq = lane >> 4;

    __shared__ __align__(16) u16 BT[128][72];   // B^T: [n][j]
    __shared__ __align__(16) u16 XwT[64][72];   // Xw^T: [p][j]
    __shared__ float sclL[QCH];

    const u16* xg = xc + (size_t)b * LSEQ * CONV_DIM;

    if (tid < 64) {
        float dtv = dtb[((size_t)b * LSEQ + t0 + tid) * HEADS + h];
        float a = -dtv * expf(A_log[h]);
        float s = a;
        #pragma unroll
        for (int off = 1; off < 64; off <<= 1) {
            float o = __shfl_up(s, off, 64);
            if (tid >= off) s += o;
        }
        float cq = __shfl(s, 63, 64);
        sclL[tid] = dtv * expf(cq - s);
        if (tid == 0) decayQ[((b * 64 + h) << 5) + c] = expf(cq);
    }
    __syncthreads();

    #pragma unroll
    for (int r = 0; r < 16; ++r) {
        int idx = tid + 256 * r, j = idx >> 6, p = idx & 63;
        float v = bf2f(xg[(size_t)(t0 + j) * CONV_DIM + h * 64 + p]);
        XwT[p][j] = f2bf(v * sclL[j]);
    }
    #pragma unroll
    for (int r = 0; r < 32; ++r) {
        int idx = tid + 256 * r, j = idx >> 7, n = idx & 127;
        BT[n][j] = xg[(size_t)(t0 + j) * CONV_DIM + INTER + n];
    }
    __syncthreads();

    f32x4 acc[8];
    #pragma unroll
    for (int i = 0; i < 8; ++i) acc[i] = (f32x4)0.f;
    #pragma unroll
    for (int k0 = 0; k0 < QCH; k0 += 32) {
        short8 af = *(const short8*)&XwT[wave * 16 + lr][k0 + lq * 8];
        #pragma unroll
        for (int nt = 0; nt < 8; ++nt) {
            short8 bfr = *(const short8*)&BT[nt * 16 + lr][k0 + lq * 8];
            acc[nt] = __builtin_amdgcn_mfma_f32_16x16x32_bf16(af, bfr, acc[nt], 0, 0, 0);
        }
    }
    // epilogue: pair lanes (lr, lr^1), pack two adjacent cols into one u32.
    u16* To = Tg + ((((size_t)(b * 64 + h)) * NCHUNK + c) * 64) * 128;
    const int odd = lr & 1;
    #pragma unroll
    for (int nt = 0; nt < 8; ++nt) {
        float v0 = acc[nt][0], v1 = acc[nt][1];
        float v2 = acc[nt][2], v3 = acc[nt][3];
        float n0v = __shfl_xor(v0, 1), n1v = __shfl_xor(v1, 1);
        float n2v = __shfl_xor(v2, 1), n3v = __shfl_xor(v3, 1);
        int colb  = nt * 16 + (lr & ~1);
        int rbase = wave * 16 + lq * 4 + odd * 2;
        u32 w0 = odd ? pack2(n2v, v2) : pack2(v0, n0v);
        u32 w1 = odd ? pack2(n3v, v3) : pack2(v1, n1v);
        *(u32*)(To + (size_t)rbase * 128 + colb) = w0;
        *(u32*)(To + (size_t)(rbase + 1) * 128 + colb) = w1;
    }
}

// ---------------------------------------------------------------------------
// SSD pass 2: sequential recurrence over chunk states (in-place).
// 512 blocks: (bh, n-quarter); each thread owns (p, 8 n-elems).
// NEW: next-chunk load hoisted above current-chunk store (breaks the
// cannot-prove-noalias serialization -> load latency overlaps the update).
// ---------------------------------------------------------------------------
__global__ __launch_bounds__(256) void ssd_state_scan(
    u16* __restrict__ Tg, const float* __restrict__ decayQ)
{
    const int bh = blockIdx.x >> 2, nq = blockIdx.x & 3;
    const int tid = threadIdx.x;
    const int p = tid >> 2, nb = nq * 32 + (tid & 3) * 8;
    float S[8];
    #pragma unroll
    for (int m = 0; m < 8; ++m) S[m] = 0.f;

    u16* base = Tg + (((size_t)bh * NCHUNK) * 64 + p) * 128 + nb;
    uint4 tv = *(const uint4*)base;
    for (int c = 0; c < NCHUNK; ++c) {
        uint4 tnext = tv;
        if (c + 1 < NCHUNK) tnext = *(const uint4*)(base + 64 * 128);
        uint4 sv;
        sv.x = pack2(S[0], S[1]);
        sv.y = pack2(S[2], S[3]);
        sv.z = pack2(S[4], S[5]);
        sv.w = pack2(S[6], S[7]);
        *(uint4*)base = sv;
        float dq = decayQ[(bh << 5) + c];
        const u32* w = (const u32*)&tv;
        #pragma unroll
        for (int e = 0; e < 4; ++e) {
            S[e*2]     = fmaf(dq, S[e*2],     bf2f((u16)(w[e] & 0xffffu)));
            S[e*2 + 1] = fmaf(dq, S[e*2 + 1], bf2f((u16)(w[e] >> 16)));
        }
        tv = tnext;
        base += 64 * 128;
    }
}

// ---------------------------------------------------------------------------
// SSD pass 3: Y = (C·B^T ∘ M)·X + diag(e^{cum})·(C·S_prev^T) + D·x.
// Round-4 staging (proven); NEW pack2-paired u32 store epilogue.
// ---------------------------------------------------------------------------
__global__ __launch_bounds__(256) void ssd_output(
    const u16* __restrict__ xc, const float* __restrict__ dtb,
    const float* __restrict__ A_log, const float* __restrict__ Dvec,
    const u16* __restrict__ Sg,
    u16* __restrict__ y)           // base xall+4096, row stride XSTR
{
    const int bid = blockIdx.x;
    const int b = bid >> 11, h = (bid >> 5) & 63, c = bid & 31;
    const int t0 = c * QCH;
    const int tid = threadIdx.x;
    const int wave = tid >> 6, lane = tid & 63;
    const int lr = lane & 15, lq = lane >> 4;

    __shared__ __align__(16) u16 C_lds[64][136];
    __shared__ __align__(16) u16 B_lds[64][136];
    __shared__ __align__(16) u16 S_lds[64][136];
    __shared__ __align__(16) u16 P_lds[64][72];
    __shared__ __align__(16) u16 XT[64][72];
    __shared__ float cumL[QCH], dtsL[QCH], escL[QCH];

    const u16* xg = xc + (size_t)b * LSEQ * CONV_DIM;

    if (tid < 64) {
        float dtv = dtb[((size_t)b * LSEQ + t0 + tid) * HEADS + h];
        float a = -dtv * expf(A_log[h]);
        float s = a;
        #pragma unroll
        for (int off = 1; off < 64; off <<= 1) {
            float o = __shfl_up(s, off, 64);
            if (tid >= off) s += o;
        }
        cumL[tid] = s;
        dtsL[tid] = dtv;
        escL[tid] = expf(s);
    }
    #pragma unroll
    for (int r4 = 0; r4 < 4; ++r4) {
        int idx4 = tid + 256 * r4;
        int j = idx4 >> 4, c8 = (idx4 & 15) * 8;
        *(uint4*)&B_lds[j][c8] = *(const uint4*)(xg + (size_t)(t0 + j) * CONV_DIM + INTER + c8);
        *(uint4*)&C_lds[j][c8] = *(const uint4*)(xg + (size_t)(t0 + j) * CONV_DIM + INTER + NSTATE + c8);
        *(uint4*)&S_lds[j][c8] = *(const uint4*)(Sg + ((((size_t)(b * 64 + h)) * NCHUNK + c) * 64 + j) * 128 + c8);
    }
    #pragma unroll
    for (int r = 0; r < 16; ++r) {
        int idx = tid + 256 * r, j = idx >> 6, p = idx & 63;
        XT[p][j] = xg[(size_t)(t0 + j) * CONV_DIM + h * 64 + p];
    }
    __syncthreads();

    f32x4 accG[4];
    #pragma unroll
    for (int i = 0; i < 4; ++i) accG[i] = (f32x4)0.f;
    #pragma unroll
    for (int k0 = 0; k0 < NSTATE; k0 += 32) {
        short8 af = *(const short8*)&C_lds[wave * 16 + lr][k0 + lq * 8];
        #pragma unroll
        for (int jt = 0; jt < 4; ++jt) {
            short8 bfr = *(const short8*)&B_lds[jt * 16 + lr][k0 + lq * 8];
            accG[jt] = __builtin_amdgcn_mfma_f32_16x16x32_bf16(af, bfr, accG[jt], 0, 0, 0);
        }
    }
    #pragma unroll
    for (int jt = 0; jt < 4; ++jt)
        #pragma unroll
        for (int r = 0; r < 4; ++r) {
            int ii = wave * 16 + lq * 4 + r;
            int jj = jt * 16 + lr;
            float v = (jj <= ii)
                ? accG[jt][r] * dtsL[jj] * expf(cumL[ii] - cumL[jj]) : 0.f;
            P_lds[ii][jj] = f2bf(v);
        }
    __syncthreads();

    f32x4 accY[4], accZ[4];
    #pragma unroll
    for (int i = 0; i < 4; ++i) { accY[i] = (f32x4)0.f; accZ[i] = (f32x4)0.f; }
    #pragma unroll
    for (int k0 = 0; k0 < QCH; k0 += 32) {
        short8 af = *(const short8*)&P_lds[wave * 16 + lr][k0 + lq * 8];
        #pragma unroll
        for (int pt = 0; pt < 4; ++pt) {
            short8 bfr = *(const short8*)&XT[pt * 16 + lr][k0 + lq * 8];
            accY[pt] = __builtin_amdgcn_mfma_f32_16x16x32_bf16(af, bfr, accY[pt], 0, 0, 0);
        }
    }
    #pragma unroll
    for (int k0 = 0; k0 < NSTATE; k0 += 32) {
        short8 af = *(const short8*)&C_lds[wave * 16 + lr][k0 + lq * 8];
        #pragma unroll
        for (int pt = 0; pt < 4; ++pt) {
            short8 bfr = *(const short8*)&S_lds[pt * 16 + lr][k0 + lq * 8];
            accZ[pt] = __builtin_amdgcn_mfma_f32_16x16x32_bf16(af, bfr, accZ[pt], 0, 0, 0);
        }
    }

    // epilogue: pair lanes (lr, lr^1), pack two adjacent p-cols into one u32.
    const float Dh = Dvec[h];
    u16* yg = y + ((size_t)b * LSEQ + t0) * XSTR + h * 64;
    const int odd = lr & 1;
    #pragma unroll
    for (int pt = 0; pt < 4; ++pt) {
        float ov[4];
        #pragma unroll
        for (int r = 0; r < 4; ++r) {
            int ii = wave * 16 + lq * 4 + r;
            int pp = pt * 16 + lr;
            float xv = bf2f(XT[pp][ii]);
            ov[r] = accY[pt][r] + escL[ii] * accZ[pt][r] + Dh * xv;
        }
        float n0v = __shfl_xor(ov[0], 1), n1v = __shfl_xor(ov[1], 1);
        float n2v = __shfl_xor(ov[2], 1), n3v = __shfl_xor(ov[3], 1);
        int ppb = pt * 16 + (lr & ~1);
        int rb  = wave * 16 + lq * 4 + odd * 2;
        u32 w0 = odd ? pack2(n2v, ov[2]) : pack2(ov[0], n0v);
        u32 w1 = odd ? pack2(n3v, ov[3]) : pack2(ov[1], n1v);
        *(u32*)(yg + (size_t)rb * XSTR + ppb) = w0;
        *(u32*)(yg + (size_t)(rb + 1) * XSTR + ppb) = w1;
    }
}

// ---------------------------------------------------------------------------
// Gated RMSNorm (G=1). y = xall cols [4096,8192), gate = cols [0,4096);
// normed bf16 written in-place over gate. Row stride XSTR. Vectorized 8/lane.
// ---------------------------------------------------------------------------
__global__ __launch_bounds__(256) void norm_kernel(
    u16* __restrict__ xall, const float* __restrict__ w)
{
    const int row = blockIdx.x;
    const u16* yr = xall + (size_t)row * XSTR + INTER;
    u16*       gr = xall + (size_t)row * XSTR;
    const int tid = threadIdx.x;

    float v[16];
    float ss = 0.f;
    #pragma unroll
    for (int i = 0; i < 2; ++i) {
        int e0 = i * 2048 + tid * 8;
        uint4 hv4 = *(const uint4*)(yr + e0);
        uint4 gv4 = *(const uint4*)(gr + e0);
        const u16* hp = (const u16*)&hv4;
        const u16* gp = (const u16*)&gv4;
        #pragma unroll
        for (int k = 0; k < 8; ++k) {
            float hv = bf2f(hp[k]);
            float g  = bf2f(gp[k]);
            float val = hv * (g / (1.f + expf(-g)));
            v[i * 8 + k] = val;
            ss = fmaf(val, val, ss);
        }
    }
    #pragma unroll
    for (int o = 32; o > 0; o >>= 1) ss += __shfl_xor(ss, o);
    __shared__ float part[4];
    if ((tid & 63) == 0) part[tid >> 6] = ss;
    __syncthreads();
    float tot  = part[0] + part[1] + part[2] + part[3];
    float rinv = rsqrtf(tot * (1.f / INTER) + EPS);
    #pragma unroll
    for (int i = 0; i < 2; ++i) {
        int e0 = i * 2048 + tid * 8;
        float4 wa = *(const float4*)(w + e0);
        float4 wb = *(const float4*)(w + e0 + 4);
        uint4 sv;
        sv.x = pack2(wa.x * v[i*8+0] * rinv, wa.y * v[i*8+1] * rinv);
        sv.y = pack2(wa.z * v[i*8+2] * rinv, wa.w * v[i*8+3] * rinv);
        sv.z = pack2(wb.x * v[i*8+4] * rinv, wb.y * v[i*8+5] * rinv);
        sv.w = pack2(wb.z * v[i*8+6] * rinv, wb.w * v[i*8+7] * rinv);
        *(uint4*)(gr + e0) = sv;
    }
}

// ---------------------------------------------------------------------------
extern "C" void kernel_launch(void* const* d_in, const int* in_sizes, int n_in,
                              void* d_out, int out_size, void* d_ws, size_t ws_size,
                              hipStream_t stream)
{
    const float* hs      = (const float*)d_in[0];
    const float* W_z     = (const float*)d_in[1];
    const float* W_xBC   = (const float*)d_in[2];
    const float* W_dt    = (const float*)d_in[3];
    const float* conv_w  = (const float*)d_in[4];
    const float* conv_b  = (const float*)d_in[5];
    const float* dt_bias = (const float*)d_in[6];
    const float* A_log   = (const float*)d_in[7];
    const float* Dv      = (const float*)d_in[8];
    const float* norm_w  = (const float*)d_in[9];
    const float* W_out   = (const float*)d_in[10];
    float* out = (float*)d_out;
    char*  w8  = (char*)d_ws;

    // workspace (bytes):
    u16* hs_bf  = (u16*)(w8 + 0);            // 16,777,216
    u16* Wt_all = (u16*)(w8 + 16777216);     // 8704*2048*2 = 35,651,584 (ends 52,428,800)
    u16* Tbuf   = (u16*)(w8 + 0);            // 67,108,864 (alias hs_bf+Wt_all; SSD phase)
    float* Cpart= (float*)(w8 + 0);          // 2*4096*2048*4 = 67,108,864 (alias; GEMM2 phase)
    u16* Wt_out = (u16*)(w8 + 67108864);     // 16,777,216
    u16* xall   = (u16*)(w8 + 83886080);     // 4096*8576*2 = 70,254,592 (ends 154,140,672)
    u16* xconv  = (u16*)(w8 + 154140672);    // 35,651,584
    float* Ptail= (float*)(w8 + 154140672);  // 4*4096*512*4 = 33,554,432 (alias xconv; dead before conv)
    float* dtb  = (float*)(w8 + 189792256);  // 1,048,576
    float* dcq  = (float*)(w8 + 190840832);  // 16,384 (total 190,857,216)

    const int M = B_SZ * LSEQ;               // 4096

    cvt_f32_bf16<<<(M * DMODEL / 4 + 255) / 256, 256, 0, stream>>>(hs, hs_bf, M * DMODEL / 4);
    // Wt_all rows: [0,4096) = W_z^T, [4096,8448) = W_xBC^T, [8448,8512) = W_dt^T,
    // [8512,8704) = zero pad (tail launch computes cols up to 8704, stores <8576)
    tr_f32_bf16<<<dim3(INTER / 64,    DMODEL / 64), 256, 0, stream>>>(W_z,   Wt_all, DMODEL, INTER);
    tr_f32_bf16<<<dim3(CONV_DIM / 64, DMODEL / 64), 256, 0, stream>>>(W_xBC, Wt_all + (size_t)INTER * DMODEL, DMODEL, CONV_DIM);
    tr_f32_bf16<<<dim3(1,             DMODEL / 64), 256, 0, stream>>>(W_dt,  Wt_all + (size_t)(INTER + CONV_DIM) * DMODEL, DMODEL, 64);
    hipMemsetAsync(Wt_all + (size_t)(INTER + CONV_DIM + 64) * DMODEL, 0, (size_t)192 * DMODEL * 2, stream);
    tr_f32_bf16<<<dim3(DMODEL / 64,   INTER / 64),  256, 0, stream>>>(W_out, Wt_out, INTER, DMODEL);

    // GEMM1 main: cols [0,8192) -> 512 blocks = exactly 2 rounds @ 1 block/CU
    gemm8<1><<<dim3(NMAIN / 256, M / 256, 1), 512, 0, stream>>>(
        hs_bf, Wt_all, (void*)xall, DMODEL /*K*/, DMODEL, DMODEL,
        XSTR /*ldc*/, NMAIN /*Nstore: all*/);
    // GEMM1 tail: cols [8192,8704), split-K=4 -> 128 blocks (K=512 each)
    gemm8<0><<<dim3(NTAILC / 256, M / 256, 4), 512, 0, stream>>>(
        hs_bf, Wt_all + (size_t)NMAIN * DMODEL, (void*)Ptail, DMODEL / 4 /*K*/,
        DMODEL, DMODEL, NTAILC /*ldc*/, NTAILS /*Nstore*/);
    tail_add<<<M * (NTAILS / 4) / 256, 256, 0, stream>>>(Ptail, xall);

    // conv (with dt folded into idle lanes)
    conv_kernel<<<dim3((CONV_DIM / 4 + 255) / 256, M), 256, 0, stream>>>(
        xall, conv_w, conv_b, xconv, dtb, dt_bias);

    ssd_chunk_state<<<B_SZ * HEADS * NCHUNK, 256, 0, stream>>>(xconv, dtb, A_log, Tbuf, dcq);
    ssd_state_scan<<<B_SZ * HEADS * 4, 256, 0, stream>>>(Tbuf, dcq);
    ssd_output<<<B_SZ * HEADS * NCHUNK, 256, 0, stream>>>(xconv, dtb, A_log, Dv, Tbuf, xall + INTER);

    norm_kernel<<<M, 256, 0, stream>>>(xall, norm_w);

    // out GEMM: split-K=2 over gridDim.z (256 blocks = 1 round), fp32 partials
    gemm8<0><<<dim3(DMODEL / 256, M / 256, 2), 512, 0, stream>>>(
        xall, Wt_out, (void*)Cpart, INTER / 2 /*K per split*/, XSTR /*lda*/,
        INTER /*ldb*/, DMODEL /*ldc*/, DMODEL /*Nstore*/);
    add2_f32<<<(M * DMODEL / 4 + 255) / 256, 256, 0, stream>>>(
        Cpart, Cpart + (size_t)M * DMODEL, out, M * DMODEL / 4);
}